// Round 11
// baseline (807.182 us; speedup 1.0000x reference)
//
#include <hip/hip_runtime.h>
#include <math.h>

#define NB 8
#define NG 2048
#define NK 32
#define NO 128
#define NM 64
#define NC 131
#define NPT (NB*NG*NK)      // 524288 positions
#define NWGT 2048           // blocks for tile passes
#define TPW 4               // tiles (of 64 positions) per workgroup

// LDS row strides (bf16 elements); octet count multiple of 8 so the
// (c>>3)^((pos>>2)&7) swizzle is closed within each row.
#define XS 136              // xT (K=128 -> 16 octets + pad)
#define ES 192              // eT (K padded 131->160 -> 24 octets)
#define HS 72               // hT (K=64 -> 8 octets + pad)
#define ZSB 136             // zb stride [pos][ch] (128 + 8 pad)

// workspace layout: floats at small offsets, xb (tile-major bf16) at +8 MB.
#define OFF_STD_PART 0
#define OFF_STD      512
#define OFF_STATA    1024
#define OFF_STATB    1536
#define OFF_STATC    2048
#define OFF_PART     4096
#define XB_BYTE_OFF  (8u << 20)

typedef __attribute__((ext_vector_type(8))) short short8v;
typedef __attribute__((ext_vector_type(4))) float f32x4;
typedef __attribute__((ext_vector_type(8))) unsigned short u16x8;

#define MFMA(a,b,c) __builtin_amdgcn_mfma_f32_16x16x32_bf16(a,b,c,0,0,0)

__device__ inline unsigned short f2bf(float f) {
  unsigned u = __builtin_bit_cast(unsigned, f);
  unsigned r = u + 0x7fffu + ((u >> 16) & 1u);
  return (unsigned short)(r >> 16);
}
__device__ inline float bf2f(unsigned short h) {
  unsigned u = ((unsigned)h) << 16;
  return __builtin_bit_cast(float, u);
}
__device__ inline int swzo(int ch, int pos) {
  return (((ch >> 3) ^ ((pos >> 2) & 7)) << 3) | (ch & 7);
}

// xb: tile-major bf16 activations in d_ws: [T][pos(64)][ch(128)]
__device__ inline size_t xb_t(int T) { return (size_t)T * (64*NO); }

// ---------------- std of rel0 (ddof=1) ----------------
__global__ __launch_bounds__(256) void k_std_part(const float* __restrict__ knn_xyz,
                                                  const float* __restrict__ lc_xyz,
                                                  float* __restrict__ part) {
  int t = threadIdx.x, blk = blockIdx.x;
  int gsz = gridDim.x * blockDim.x;
  float s = 0.f, s2 = 0.f;
  for (int i = blk*256 + t; i < NPT*3; i += gsz) {
    int d = i % 3;
    int pk = i / 3;
    int bg = pk / NK;
    float r = knn_xyz[i] - lc_xyz[bg*3 + d];
    s += r; s2 += r*r;
  }
  __shared__ float ls[256], ls2[256];
  ls[t] = s; ls2[t] = s2; __syncthreads();
  for (int off = 128; off >= 1; off >>= 1) {
    if (t < off) { ls[t] += ls[t+off]; ls2[t] += ls2[t+off]; }
    __syncthreads();
  }
  if (t == 0) { part[blk*2] = ls[0]; part[blk*2+1] = ls2[0]; }
}

__global__ __launch_bounds__(256) void k_std_fin(const float* __restrict__ part,
                                                 float* __restrict__ wsc) {
  int t = threadIdx.x;
  __shared__ float ls[256], ls2[256];
  ls[t] = part[t*2]; ls2[t] = part[t*2+1]; __syncthreads();
  for (int off = 128; off >= 1; off >>= 1) {
    if (t < off) { ls[t] += ls[t+off]; ls2[t] += ls2[t+off]; }
    __syncthreads();
  }
  if (t == 0) {
    double S = ls[0], S2 = ls2[0];
    double n = (double)NPT * 3.0;
    double var = (S2 - S*S/n) / (n - 1.0);
    wsc[0] = (float)(sqrt(var) + 1e-5);
  }
}

// ---------------- BN finalize ----------------
__global__ __launch_bounds__(256) void k_fin_bn(const float* __restrict__ part, int C, int nrows,
                                                const float* __restrict__ gamma,
                                                const float* __restrict__ beta,
                                                float* __restrict__ stat) {
  int o = blockIdx.x, t = threadIdx.x;
  float s = 0.f, s2 = 0.f;
  for (int r = t; r < nrows; r += 256) {
    s  += part[((size_t)r*C + o)*2 + 0];
    s2 += part[((size_t)r*C + o)*2 + 1];
  }
  __shared__ float ls[256], ls2[256];
  ls[t] = s; ls2[t] = s2; __syncthreads();
  for (int off = 128; off >= 1; off >>= 1) {
    if (t < off) { ls[t] += ls[t+off]; ls2[t] += ls2[t+off]; }
    __syncthreads();
  }
  if (t == 0) {
    float n = (float)NPT;
    float mean = ls[0] / n;
    float var  = ls2[0] / n - mean*mean;
    float sc = gamma[o] * rsqrtf(var + 1e-5f);
    stat[o*2]   = sc;
    stat[o*2+1] = beta[o] - mean*sc;
  }
}

// ---------------- z1 = expanded @ W1^T -> xb [pos][ch], BN1 partials ----------------
__global__ __launch_bounds__(256,4) void k_z1(const float* __restrict__ knn_feat,
                                              const float* __restrict__ lc_feat,
                                              const float* __restrict__ w1,
                                              unsigned short* __restrict__ xb,
                                              float* __restrict__ part) {
  __shared__ __align__(16) unsigned short shmem[64*ES];  // 24576 B; overlaid eT / zb
  unsigned short* eT = shmem;
  unsigned short* zb = shmem;   // [pos][ZSB]
  int t = threadIdx.x, blk = blockIdx.x;
  int lane = t & 63, w = t >> 6;
  int p = lane & 15, q = lane >> 4;

  short8v wf[2][5];
#pragma unroll
  for (int ntl = 0; ntl < 2; ++ntl)
#pragma unroll
    for (int ks = 0; ks < 5; ++ks) {
      int row = w*32 + ntl*16 + p;
      int kb = ks*32 + q*8;
      short8v f;
#pragma unroll
      for (int j = 0; j < 8; ++j) {
        int k = kb + j;
        f[j] = (short)((k < NC) ? f2bf(w1[row*NC + k]) : 0);
      }
      wf[ntl][ks] = f;
    }

  float ss[2] = {0.f, 0.f}, ss2[2] = {0.f, 0.f};

  for (int gi = 0; gi < TPW; ++gi) {
    int T = blk*TPW + gi;
    int bg0 = T*2;
    __syncthreads();      // protects eT write vs previous zb reads
    const float* kf = knn_feat + (size_t)bg0*NK*67;
    for (int i = t; i < 64*67; i += 256) {
      int pos = i/67, c = i - pos*67;
      eT[pos*ES + swzo(c, pos)] = f2bf(kf[i]);
    }
    const float* lf = lc_feat + (size_t)bg0*64;
    for (int i = t; i < 64*64; i += 256) {
      int pos = i >> 6, c = i & 63;
      eT[pos*ES + swzo(67 + c, pos)] = f2bf(lf[(pos>>5)*64 + c]);
    }
    for (int i = t; i < 64*32; i += 256) {
      int pos = i >> 5, c = 131 + (i & 31);
      if (c < 160) eT[pos*ES + swzo(c, pos)] = 0;
    }
    __syncthreads();

    f32x4 acc[4][2];
#pragma unroll
    for (int mt = 0; mt < 4; ++mt)
#pragma unroll
      for (int ntl = 0; ntl < 2; ++ntl) acc[mt][ntl] = (f32x4){0.f,0.f,0.f,0.f};
#pragma unroll
    for (int ks = 0; ks < 5; ++ks)
#pragma unroll
      for (int mt = 0; mt < 4; ++mt) {
        int pos = mt*16 + p;
        short8v a = *(const short8v*)&eT[pos*ES + (((ks*4+q) ^ ((pos>>2)&7))<<3)];
#pragma unroll
        for (int ntl = 0; ntl < 2; ++ntl) acc[mt][ntl] = MFMA(a, wf[ntl][ks], acc[mt][ntl]);
      }
    __syncthreads();      // eT reads done before zb overwrite
#pragma unroll
    for (int ntl = 0; ntl < 2; ++ntl) {
      int ch = w*32 + ntl*16 + p;
#pragma unroll
      for (int mt = 0; mt < 4; ++mt)
#pragma unroll
        for (int r = 0; r < 4; ++r) {
          float v = acc[mt][ntl][r];
          ss[ntl] += v; ss2[ntl] += v*v;
          zb[(mt*16 + q*4 + r)*ZSB + ch] = f2bf(v);
        }
    }
    __syncthreads();
#pragma unroll
    for (int it = 0; it < 4; ++it) {
      int pos = (t>>4) + it*16;
      int c8 = (t & 15)*8;
      *(u16x8*)&xb[xb_t(T) + pos*NO + c8] = *(const u16x8*)&zb[pos*ZSB + c8];
    }
  }
#pragma unroll
  for (int ntl = 0; ntl < 2; ++ntl) {
    float v = ss[ntl], v2 = ss2[ntl];
    v += __shfl_xor(v, 16); v += __shfl_xor(v, 32);
    v2 += __shfl_xor(v2, 16); v2 += __shfl_xor(v2, 32);
    if (q == 0) {
      int ch = w*32 + ntl*16 + p;
      part[((size_t)blk*NO + ch)*2 + 0] = v;
      part[((size_t)blk*NO + ch)*2 + 1] = v2;
    }
  }
}

// ---------------- x1 = relu(bn1(z1))*wgt (in place in xb) + down0 partials ----------------
__global__ __launch_bounds__(256,5) void k_x1(const float* __restrict__ knn_xyz,
                                              const float* __restrict__ lc_xyz,
                                              const float* __restrict__ wd,
                                              const float* __restrict__ bd,
                                              unsigned short* __restrict__ xb,
                                              const float* __restrict__ wsc,
                                              const float* __restrict__ bn1_stat,
                                              float* __restrict__ part) {
  __shared__ __align__(16) unsigned short xT[64*XS];
  __shared__ float s_wgt4[TPW*64];
  int t = threadIdx.x, blk = blockIdx.x;
  int lane = t & 63, w = t >> 6;
  int p = lane & 15, q = lane >> 4;
  int pos0 = t >> 4, ch8 = (t & 15)*8, oct = t & 15;

  short8v wfd[4];
#pragma unroll
  for (int ks = 0; ks < 4; ++ks) {
    short8v f;
#pragma unroll
    for (int j = 0; j < 8; ++j) f[j] = (short)f2bf(wd[(w*16+p)*NO + ks*32 + q*8 + j]);
    wfd[ks] = f;
  }
  float sc[8], sh[8];
#pragma unroll
  for (int e = 0; e < 8; ++e) { sc[e] = bn1_stat[(ch8+e)*2]; sh[e] = bn1_stat[(ch8+e)*2+1]; }
  float bdv = bd[w*16 + p];
  float inv_std = 1.0f / wsc[0];

  // gauss weights for all TPW tiles in one shot (t -> tile t>>6, pos t&63)
  {
    int gi4 = t >> 6, pp = t & 63;
    int bg0 = (blk*TPW + gi4)*2;
    const float* kx = knn_xyz + ((size_t)bg0*NK + pp)*3;
    const float* lc = lc_xyz + ((size_t)bg0 + (pp>>5))*3;
    float d2 = 0.f;
#pragma unroll
    for (int d = 0; d < 3; ++d) { float r = (kx[d]-lc[d])*inv_std - lc[d]; d2 += r*r; }
    s_wgt4[t] = expf(-sqrtf(d2)*0.5f);
  }

  float ss = 0.f, ss2 = 0.f;

  for (int gi = 0; gi < TPW; ++gi) {
    int T = blk*TPW + gi;
    __syncthreads();     // s_wgt4 ready (gi=0) / prev xT reads done
    const unsigned short* s = xb + xb_t(T);
    unsigned short* dst = xb + xb_t(T);
    u16x8 v0 = *(const u16x8*)&s[(pos0 +  0)*NO + ch8];
    u16x8 v1 = *(const u16x8*)&s[(pos0 + 16)*NO + ch8];
    u16x8 v2 = *(const u16x8*)&s[(pos0 + 32)*NO + ch8];
    u16x8 v3 = *(const u16x8*)&s[(pos0 + 48)*NO + ch8];
#define XF(NV, POFF) { int pos = pos0 + POFF;                                   \
      float wg = s_wgt4[gi*64 + pos]; u16x8 ov;                                 \
      _Pragma("unroll") for (int e = 0; e < 8; ++e) {                           \
        float v = fmaxf(bf2f(NV[e])*sc[e] + sh[e], 0.f) * wg; ov[e] = f2bf(v); }\
      *(u16x8*)&xT[pos*XS + ((oct ^ ((pos>>2)&7))<<3)] = ov;                    \
      *(u16x8*)&dst[pos*NO + ch8] = ov; }
    XF(v0, 0) XF(v1, 16) XF(v2, 32) XF(v3, 48)
#undef XF
    __syncthreads();     // xT visible
    f32x4 acc[4];
#pragma unroll
    for (int mt = 0; mt < 4; ++mt) acc[mt] = (f32x4){0.f,0.f,0.f,0.f};
#pragma unroll
    for (int ks = 0; ks < 4; ++ks)
#pragma unroll
      for (int mt = 0; mt < 4; ++mt) {
        int pos = mt*16 + p;
        short8v a = *(const short8v*)&xT[pos*XS + (((ks*4+q) ^ ((pos>>2)&7))<<3)];
        acc[mt] = MFMA(a, wfd[ks], acc[mt]);
      }
#pragma unroll
    for (int mt = 0; mt < 4; ++mt)
#pragma unroll
      for (int r = 0; r < 4; ++r) { float v = acc[mt][r] + bdv; ss += v; ss2 += v*v; }
  }
  ss += __shfl_xor(ss, 16); ss += __shfl_xor(ss, 32);
  ss2 += __shfl_xor(ss2, 16); ss2 += __shfl_xor(ss2, 32);
  if (q == 0) {
    part[((size_t)blk*NM + w*16 + p)*2 + 0] = ss;
    part[((size_t)blk*NM + w*16 + p)*2 + 1] = ss2;
  }
}

// ---------------- pass B: down+up recompute, u_pre partials ----------------
__global__ __launch_bounds__(256,6) void k_bstat(const unsigned short* __restrict__ xb,
                                                 const float* __restrict__ wd,
                                                 const float* __restrict__ bd,
                                                 const float* __restrict__ wu,
                                                 const float* __restrict__ bu,
                                                 const float* __restrict__ bnd_stat,
                                                 float* __restrict__ part) {
  __shared__ __align__(16) unsigned short xT[64*XS];
  __shared__ __align__(16) unsigned short hT[64*HS];
  __shared__ float s_bu[NO];
  int t = threadIdx.x, blk = blockIdx.x;
  int lane = t & 63, w = t >> 6;
  int p = lane & 15, q = lane >> 4;
  int pos0 = t >> 4, ch8 = (t & 15)*8, oct = t & 15;

  short8v wfd[4];
#pragma unroll
  for (int ks = 0; ks < 4; ++ks) {
    short8v f;
#pragma unroll
    for (int j = 0; j < 8; ++j) f[j] = (short)f2bf(wd[(w*16+p)*NO + ks*32 + q*8 + j]);
    wfd[ks] = f;
  }
  short8v wfu[2][2];
#pragma unroll
  for (int ntl = 0; ntl < 2; ++ntl)
#pragma unroll
    for (int ks = 0; ks < 2; ++ks) {
      short8v f;
#pragma unroll
      for (int j = 0; j < 8; ++j) f[j] = (short)f2bf(wu[(w*32+ntl*16+p)*NM + ks*32 + q*8 + j]);
      wfu[ntl][ks] = f;
    }
  for (int i = t; i < NO; i += 256) s_bu[i] = bu[i];
  float c1 = bnd_stat[(w*16+p)*2];
  float c0 = bd[w*16+p]*c1 + bnd_stat[(w*16+p)*2+1];

  float ss[2] = {0.f,0.f}, ss2[2] = {0.f,0.f};

  for (int gi = 0; gi < TPW; ++gi) {
    int T = blk*TPW + gi;
    __syncthreads();
    const unsigned short* s = xb + xb_t(T);
    u16x8 v0 = *(const u16x8*)&s[(pos0 +  0)*NO + ch8];
    u16x8 v1 = *(const u16x8*)&s[(pos0 + 16)*NO + ch8];
    u16x8 v2 = *(const u16x8*)&s[(pos0 + 32)*NO + ch8];
    u16x8 v3 = *(const u16x8*)&s[(pos0 + 48)*NO + ch8];
#define ST(NV, POFF) { int pos = pos0 + POFF; \
      *(u16x8*)&xT[pos*XS + ((oct ^ ((pos>>2)&7))<<3)] = NV; }
    ST(v0, 0) ST(v1, 16) ST(v2, 32) ST(v3, 48)
#undef ST
    __syncthreads();
    {
      f32x4 dacc[4];
#pragma unroll
      for (int mt = 0; mt < 4; ++mt) dacc[mt] = (f32x4){0.f,0.f,0.f,0.f};
#pragma unroll
      for (int ks = 0; ks < 4; ++ks)
#pragma unroll
        for (int mt = 0; mt < 4; ++mt) {
          int pos = mt*16 + p;
          short8v a = *(const short8v*)&xT[pos*XS + (((ks*4+q) ^ ((pos>>2)&7))<<3)];
          dacc[mt] = MFMA(a, wfd[ks], dacc[mt]);
        }
      int ch = w*16 + p;
#pragma unroll
      for (int mt = 0; mt < 4; ++mt)
#pragma unroll
        for (int r = 0; r < 4; ++r) {
          int pos = mt*16 + q*4 + r;
          hT[pos*HS + swzo(ch, pos)] = f2bf(fmaxf(dacc[mt][r]*c1 + c0, 0.f));
        }
    }
    __syncthreads();
    {
      f32x4 uacc[4][2];
#pragma unroll
      for (int mt = 0; mt < 4; ++mt)
#pragma unroll
        for (int ntl = 0; ntl < 2; ++ntl) uacc[mt][ntl] = (f32x4){0.f,0.f,0.f,0.f};
#pragma unroll
      for (int ks = 0; ks < 2; ++ks)
#pragma unroll
        for (int mt = 0; mt < 4; ++mt) {
          int pos = mt*16 + p;
          short8v a = *(const short8v*)&hT[pos*HS + (((ks*4+q) ^ ((pos>>2)&7))<<3)];
#pragma unroll
          for (int ntl = 0; ntl < 2; ++ntl) uacc[mt][ntl] = MFMA(a, wfu[ntl][ks], uacc[mt][ntl]);
        }
#pragma unroll
      for (int ntl = 0; ntl < 2; ++ntl) {
        float buv = s_bu[w*32 + ntl*16 + p];
#pragma unroll
        for (int mt = 0; mt < 4; ++mt)
#pragma unroll
          for (int r = 0; r < 4; ++r) { float v = uacc[mt][ntl][r] + buv; ss[ntl] += v; ss2[ntl] += v*v; }
      }
    }
  }
#pragma unroll
  for (int ntl = 0; ntl < 2; ++ntl) {
    float v = ss[ntl], v2 = ss2[ntl];
    v += __shfl_xor(v, 16); v += __shfl_xor(v, 32);
    v2 += __shfl_xor(v2, 16); v2 += __shfl_xor(v2, 32);
    if (q == 0) {
      int ch = w*32 + ntl*16 + p;
      part[((size_t)blk*NO + ch)*2 + 0] = v;
      part[((size_t)blk*NO + ch)*2 + 1] = v2;
    }
  }
}

// ---------------- pass C: full block + residual; write xb or final f32 ----------------
__global__ __launch_bounds__(256,5) void k_bfin(unsigned short* __restrict__ xb,
                                                float* __restrict__ out,
                                                const float* __restrict__ wd,
                                                const float* __restrict__ bd,
                                                const float* __restrict__ wu,
                                                const float* __restrict__ bu,
                                                const float* __restrict__ bnd_stat,
                                                const float* __restrict__ bnu_stat,
                                                const float* __restrict__ wdn,
                                                const float* __restrict__ bdn,
                                                float* __restrict__ part,
                                                int do_next) {
  __shared__ __align__(16) unsigned short xT[64*XS];
  __shared__ __align__(16) unsigned short hT[64*HS];
  __shared__ float s_u1[NO], s_u0[NO];
  int t = threadIdx.x, blk = blockIdx.x;
  int lane = t & 63, w = t >> 6;
  int p = lane & 15, q = lane >> 4;
  int pos0 = t >> 4, ch8 = (t & 15)*8, oct = t & 15;

  short8v wfd[4];
#pragma unroll
  for (int ks = 0; ks < 4; ++ks) {
    short8v f;
#pragma unroll
    for (int j = 0; j < 8; ++j) f[j] = (short)f2bf(wd[(w*16+p)*NO + ks*32 + q*8 + j]);
    wfd[ks] = f;
  }
  short8v wfu[2][2];
#pragma unroll
  for (int ntl = 0; ntl < 2; ++ntl)
#pragma unroll
    for (int ks = 0; ks < 2; ++ks) {
      short8v f;
#pragma unroll
      for (int j = 0; j < 8; ++j) f[j] = (short)f2bf(wu[(w*32+ntl*16+p)*NM + ks*32 + q*8 + j]);
      wfu[ntl][ks] = f;
    }
  short8v wfn[4];
  if (do_next) {
#pragma unroll
    for (int ks = 0; ks < 4; ++ks) {
      short8v f;
#pragma unroll
      for (int j = 0; j < 8; ++j) f[j] = (short)f2bf(wdn[(w*16+p)*NO + ks*32 + q*8 + j]);
      wfn[ks] = f;
    }
  }
  float c1 = bnd_stat[(w*16+p)*2];
  float c0 = bd[w*16+p]*c1 + bnd_stat[(w*16+p)*2+1];
  float bdnv = do_next ? bdn[w*16+p] : 0.f;
  for (int i = t; i < NO; i += 256) {
    float scv = bnu_stat[i*2];
    s_u1[i] = scv; s_u0[i] = bu[i]*scv + bnu_stat[i*2+1];
  }

  float ss = 0.f, ss2 = 0.f;

  for (int gi = 0; gi < TPW; ++gi) {
    int T = blk*TPW + gi;
    int bg0 = T*2;
    int b = bg0 >> 11, g0 = bg0 & (NG-1);
    __syncthreads();
    const unsigned short* s = xb + xb_t(T);
    u16x8 v0 = *(const u16x8*)&s[(pos0 +  0)*NO + ch8];
    u16x8 v1 = *(const u16x8*)&s[(pos0 + 16)*NO + ch8];
    u16x8 v2 = *(const u16x8*)&s[(pos0 + 32)*NO + ch8];
    u16x8 v3 = *(const u16x8*)&s[(pos0 + 48)*NO + ch8];
#define ST(NV, POFF) { int pos = pos0 + POFF; \
      *(u16x8*)&xT[pos*XS + ((oct ^ ((pos>>2)&7))<<3)] = NV; }
    ST(v0, 0) ST(v1, 16) ST(v2, 32) ST(v3, 48)
#undef ST
    __syncthreads();
    // down -> hT
    {
      f32x4 dacc[4];
#pragma unroll
      for (int mt = 0; mt < 4; ++mt) dacc[mt] = (f32x4){0.f,0.f,0.f,0.f};
#pragma unroll
      for (int ks = 0; ks < 4; ++ks)
#pragma unroll
        for (int mt = 0; mt < 4; ++mt) {
          int pos = mt*16 + p;
          short8v a = *(const short8v*)&xT[pos*XS + (((ks*4+q) ^ ((pos>>2)&7))<<3)];
          dacc[mt] = MFMA(a, wfd[ks], dacc[mt]);
        }
      int ch = w*16 + p;
#pragma unroll
      for (int mt = 0; mt < 4; ++mt)
#pragma unroll
        for (int r = 0; r < 4; ++r) {
          int pos = mt*16 + q*4 + r;
          hT[pos*HS + swzo(ch, pos)] = f2bf(fmaxf(dacc[mt][r]*c1 + c0, 0.f));
        }
    }
    __syncthreads();
    // up + residual in fragment layout, write x_new back into xT
    {
      f32x4 uacc[4][2];
#pragma unroll
      for (int mt = 0; mt < 4; ++mt)
#pragma unroll
        for (int ntl = 0; ntl < 2; ++ntl) uacc[mt][ntl] = (f32x4){0.f,0.f,0.f,0.f};
#pragma unroll
      for (int ks = 0; ks < 2; ++ks)
#pragma unroll
        for (int mt = 0; mt < 4; ++mt) {
          int pos = mt*16 + p;
          short8v a = *(const short8v*)&hT[pos*HS + (((ks*4+q) ^ ((pos>>2)&7))<<3)];
#pragma unroll
          for (int ntl = 0; ntl < 2; ++ntl) uacc[mt][ntl] = MFMA(a, wfu[ntl][ks], uacc[mt][ntl]);
        }
#pragma unroll
      for (int ntl = 0; ntl < 2; ++ntl) {
        int ch = w*32 + ntl*16 + p;
        float u1 = s_u1[ch], u0 = s_u0[ch];
#pragma unroll
        for (int mt = 0; mt < 4; ++mt)
#pragma unroll
          for (int r = 0; r < 4; ++r) {
            int pos = mt*16 + q*4 + r;
            int off = pos*XS + swzo(ch, pos);
            float u = uacc[mt][ntl][r]*u1 + u0;
            float xn = fmaxf(u + bf2f(xT[off]), 0.f);
            xT[off] = f2bf(xn);
          }
      }
    }
    __syncthreads();
    if (do_next) {
      unsigned short* dst = xb + xb_t(T);
#pragma unroll
      for (int it = 0; it < 4; ++it) {
        int pos = pos0 + it*16;
        u16x8 ov = *(const u16x8*)&xT[pos*XS + ((oct ^ ((pos>>2)&7))<<3)];
        *(u16x8*)&dst[pos*NO + ch8] = ov;
      }
      f32x4 nacc[4];
#pragma unroll
      for (int mt = 0; mt < 4; ++mt) nacc[mt] = (f32x4){0.f,0.f,0.f,0.f};
#pragma unroll
      for (int ks = 0; ks < 4; ++ks)
#pragma unroll
        for (int mt = 0; mt < 4; ++mt) {
          int pos = mt*16 + p;
          short8v a = *(const short8v*)&xT[pos*XS + (((ks*4+q) ^ ((pos>>2)&7))<<3)];
          nacc[mt] = MFMA(a, wfn[ks], nacc[mt]);
        }
#pragma unroll
      for (int mt = 0; mt < 4; ++mt)
#pragma unroll
        for (int r = 0; r < 4; ++r) { float v = nacc[mt][r] + bdnv; ss += v; ss2 += v*v; }
    } else {
      // final f32 output
#pragma unroll
      for (int it = 0; it < 8; ++it) {
        int i = t + it*256;
        int ch = i >> 4, p4 = (i & 15)*4;
        f32x4 o;
#pragma unroll
        for (int r = 0; r < 4; ++r) o[r] = bf2f(xT[(p4+r)*XS + swzo(ch, p4+r)]);
        *(f32x4*)&out[(((size_t)b*NO + ch)*NG + g0)*NK + p4] = o;
      }
    }
  }
  if (do_next) {
    ss += __shfl_xor(ss, 16); ss += __shfl_xor(ss, 32);
    ss2 += __shfl_xor(ss2, 16); ss2 += __shfl_xor(ss2, 32);
    if (q == 0) {
      part[((size_t)blk*NM + w*16 + p)*2 + 0] = ss;
      part[((size_t)blk*NM + w*16 + p)*2 + 1] = ss2;
    }
  }
}

extern "C" void kernel_launch(void* const* d_in, const int* in_sizes, int n_in,
                              void* d_out, int out_size, void* d_ws, size_t ws_size,
                              hipStream_t stream) {
  const float* lc_xyz   = (const float*)d_in[0];
  const float* lc_feat  = (const float*)d_in[1];
  const float* knn_xyz  = (const float*)d_in[2];
  const float* knn_feat = (const float*)d_in[3];
  const float* w1       = (const float*)d_in[4];
  const float* bn1_g    = (const float*)d_in[5];
  const float* bn1_b    = (const float*)d_in[6];
  const float* wd       = (const float*)d_in[7];
  const float* bd       = (const float*)d_in[8];
  const float* dn_g     = (const float*)d_in[9];
  const float* dn_b     = (const float*)d_in[10];
  const float* wu       = (const float*)d_in[11];
  const float* bu       = (const float*)d_in[12];
  const float* up_g     = (const float*)d_in[13];
  const float* up_b     = (const float*)d_in[14];
  float* out = (float*)d_out;
  float* ws  = (float*)d_ws;
  unsigned short* xb = (unsigned short*)((char*)d_ws + XB_BYTE_OFF);

  k_std_part<<<256, 256, 0, stream>>>(knn_xyz, lc_xyz, ws + OFF_STD_PART);
  k_std_fin<<<1, 256, 0, stream>>>(ws + OFF_STD_PART, ws + OFF_STD);

  k_z1<<<NWGT, 256, 0, stream>>>(knn_feat, lc_feat, w1, xb, ws + OFF_PART);
  k_fin_bn<<<128, 256, 0, stream>>>(ws + OFF_PART, 128, NWGT, bn1_g, bn1_b, ws + OFF_STATA);

  k_x1<<<NWGT, 256, 0, stream>>>(knn_xyz, lc_xyz, wd, bd, xb, ws + OFF_STD,
                                 ws + OFF_STATA, ws + OFF_PART);
  k_fin_bn<<<64, 256, 0, stream>>>(ws + OFF_PART, 64, NWGT, dn_g, dn_b, ws + OFF_STATB);

  k_bstat<<<NWGT, 256, 0, stream>>>(xb, wd, bd, wu, bu, ws + OFF_STATB, ws + OFF_PART);
  k_fin_bn<<<128, 256, 0, stream>>>(ws + OFF_PART, 128, NWGT, up_g, up_b, ws + OFF_STATC);

  k_bfin<<<NWGT, 256, 0, stream>>>(xb, out, wd, bd, wu, bu, ws + OFF_STATB, ws + OFF_STATC,
                                   wd + 64*128, bd + 64, ws + OFF_PART, 1);
  k_fin_bn<<<64, 256, 0, stream>>>(ws + OFF_PART, 64, NWGT, dn_g + 64, dn_b + 64, ws + OFF_STATB);

  k_bstat<<<NWGT, 256, 0, stream>>>(xb, wd + 64*128, bd + 64, wu + 128*64, bu + 128,
                                    ws + OFF_STATB, ws + OFF_PART);
  k_fin_bn<<<128, 256, 0, stream>>>(ws + OFF_PART, 128, NWGT, up_g + 128, up_b + 128, ws + OFF_STATC);

  k_bfin<<<NWGT, 256, 0, stream>>>(xb, out, wd + 64*128, bd + 64, wu + 128*64, bu + 128,
                                   ws + OFF_STATB, ws + OFF_STATC,
                                   (const float*)nullptr, (const float*)nullptr,
                                   ws + OFF_PART, 0);
}

// Round 12
// 454.825 us; speedup vs baseline: 1.7747x; 1.7747x over previous
//
#include <hip/hip_runtime.h>
#include <math.h>

#define NB 8
#define NG 2048
#define NK 32
#define NO 128
#define NM 64
#define NC 131
#define NPT (NB*NG*NK)      // 524288 positions
#define NWGT 2048           // blocks for tile passes
#define TPW 4               // tiles (of 64 positions) per workgroup

// LDS row strides (bf16 elements); octet count multiple of 8 so the
// (c>>3)^((pos>>2)&7) swizzle is closed within each row.
#define XS 136              // xT (K=128 -> 16 octets + pad)
#define ES 192              // eT (K padded 131->160 -> 24 octets)
#define HS 72               // hT (K=64 -> 8 octets + pad)
#define ZSB 136             // zb stride [pos][ch] (128 + 8 pad)

// workspace layout: floats at small offsets, xb (tile-major bf16) at +8 MB.
#define OFF_STD_PART 0
#define OFF_STD      512
#define OFF_STATA    1024
#define OFF_STATB    1536
#define OFF_STATC    2048
#define OFF_PART     4096
#define XB_BYTE_OFF  (8u << 20)

typedef __attribute__((ext_vector_type(8))) short short8v;
typedef __attribute__((ext_vector_type(4))) float f32x4;
typedef __attribute__((ext_vector_type(8))) unsigned short u16x8;

#define MFMA(a,b,c) __builtin_amdgcn_mfma_f32_16x16x32_bf16(a,b,c,0,0,0)

__device__ inline unsigned short f2bf(float f) {
  unsigned u = __builtin_bit_cast(unsigned, f);
  unsigned r = u + 0x7fffu + ((u >> 16) & 1u);
  return (unsigned short)(r >> 16);
}
__device__ inline float bf2f(unsigned short h) {
  unsigned u = ((unsigned)h) << 16;
  return __builtin_bit_cast(float, u);
}
__device__ inline int swzo(int ch, int pos) {
  return (((ch >> 3) ^ ((pos >> 2) & 7)) << 3) | (ch & 7);
}

// xb: tile-major bf16 activations in d_ws: [T][pos(64)][ch(128)]
__device__ inline size_t xb_t(int T) { return (size_t)T * (64*NO); }

// ---------------- std of rel0 (ddof=1) ----------------
__global__ __launch_bounds__(256) void k_std_part(const float* __restrict__ knn_xyz,
                                                  const float* __restrict__ lc_xyz,
                                                  float* __restrict__ part) {
  int t = threadIdx.x, blk = blockIdx.x;
  int gsz = gridDim.x * blockDim.x;
  float s = 0.f, s2 = 0.f;
  for (int i = blk*256 + t; i < NPT*3; i += gsz) {
    int d = i % 3;
    int pk = i / 3;
    int bg = pk / NK;
    float r = knn_xyz[i] - lc_xyz[bg*3 + d];
    s += r; s2 += r*r;
  }
  __shared__ float ls[256], ls2[256];
  ls[t] = s; ls2[t] = s2; __syncthreads();
  for (int off = 128; off >= 1; off >>= 1) {
    if (t < off) { ls[t] += ls[t+off]; ls2[t] += ls2[t+off]; }
    __syncthreads();
  }
  if (t == 0) { part[blk*2] = ls[0]; part[blk*2+1] = ls2[0]; }
}

__global__ __launch_bounds__(256) void k_std_fin(const float* __restrict__ part,
                                                 float* __restrict__ wsc) {
  int t = threadIdx.x;
  __shared__ float ls[256], ls2[256];
  ls[t] = part[t*2]; ls2[t] = part[t*2+1]; __syncthreads();
  for (int off = 128; off >= 1; off >>= 1) {
    if (t < off) { ls[t] += ls[t+off]; ls2[t] += ls2[t+off]; }
    __syncthreads();
  }
  if (t == 0) {
    double S = ls[0], S2 = ls2[0];
    double n = (double)NPT * 3.0;
    double var = (S2 - S*S/n) / (n - 1.0);
    wsc[0] = (float)(sqrt(var) + 1e-5);
  }
}

// ---------------- BN finalize ----------------
__global__ __launch_bounds__(256) void k_fin_bn(const float* __restrict__ part, int C, int nrows,
                                                const float* __restrict__ gamma,
                                                const float* __restrict__ beta,
                                                float* __restrict__ stat) {
  int o = blockIdx.x, t = threadIdx.x;
  float s = 0.f, s2 = 0.f;
  for (int r = t; r < nrows; r += 256) {
    s  += part[((size_t)r*C + o)*2 + 0];
    s2 += part[((size_t)r*C + o)*2 + 1];
  }
  __shared__ float ls[256], ls2[256];
  ls[t] = s; ls2[t] = s2; __syncthreads();
  for (int off = 128; off >= 1; off >>= 1) {
    if (t < off) { ls[t] += ls[t+off]; ls2[t] += ls2[t+off]; }
    __syncthreads();
  }
  if (t == 0) {
    float n = (float)NPT;
    float mean = ls[0] / n;
    float var  = ls2[0] / n - mean*mean;
    float sc = gamma[o] * rsqrtf(var + 1e-5f);
    stat[o*2]   = sc;
    stat[o*2+1] = beta[o] - mean*sc;
  }
}

// ---------------- z1 = expanded @ W1^T -> xb [pos][ch], BN1 partials ----------------
__global__ __launch_bounds__(256,4) void k_z1(const float* __restrict__ knn_feat,
                                              const float* __restrict__ lc_feat,
                                              const float* __restrict__ w1,
                                              unsigned short* __restrict__ xb,
                                              float* __restrict__ part) {
  __shared__ __align__(16) unsigned short shmem[64*ES];  // 24576 B; overlaid eT / zb
  unsigned short* eT = shmem;
  unsigned short* zb = shmem;   // [pos][ZSB]
  int t = threadIdx.x, blk = blockIdx.x;
  int lane = t & 63, w = t >> 6;
  int p = lane & 15, q = lane >> 4;

  short8v wf[2][5];
#pragma unroll
  for (int ntl = 0; ntl < 2; ++ntl)
#pragma unroll
    for (int ks = 0; ks < 5; ++ks) {
      int row = w*32 + ntl*16 + p;
      int kb = ks*32 + q*8;
      short8v f;
#pragma unroll
      for (int j = 0; j < 8; ++j) {
        int k = kb + j;
        f[j] = (short)((k < NC) ? f2bf(w1[row*NC + k]) : 0);
      }
      wf[ntl][ks] = f;
    }

  float ss[2] = {0.f, 0.f}, ss2[2] = {0.f, 0.f};

  for (int gi = 0; gi < TPW; ++gi) {
    int T = blk*TPW + gi;
    int bg0 = T*2;
    __syncthreads();      // protects eT write vs previous zb reads
    const float* kf = knn_feat + (size_t)bg0*NK*67;
    for (int i = t; i < 64*67; i += 256) {
      int pos = i/67, c = i - pos*67;
      eT[pos*ES + swzo(c, pos)] = f2bf(kf[i]);
    }
    const float* lf = lc_feat + (size_t)bg0*64;
    for (int i = t; i < 64*64; i += 256) {
      int pos = i >> 6, c = i & 63;
      eT[pos*ES + swzo(67 + c, pos)] = f2bf(lf[(pos>>5)*64 + c]);
    }
    for (int i = t; i < 64*32; i += 256) {
      int pos = i >> 5, c = 131 + (i & 31);
      if (c < 160) eT[pos*ES + swzo(c, pos)] = 0;
    }
    __syncthreads();

    f32x4 acc[4][2];
#pragma unroll
    for (int mt = 0; mt < 4; ++mt)
#pragma unroll
      for (int ntl = 0; ntl < 2; ++ntl) acc[mt][ntl] = (f32x4){0.f,0.f,0.f,0.f};
#pragma unroll
    for (int ks = 0; ks < 5; ++ks)
#pragma unroll
      for (int mt = 0; mt < 4; ++mt) {
        int pos = mt*16 + p;
        short8v a = *(const short8v*)&eT[pos*ES + (((ks*4+q) ^ ((pos>>2)&7))<<3)];
#pragma unroll
        for (int ntl = 0; ntl < 2; ++ntl) acc[mt][ntl] = MFMA(a, wf[ntl][ks], acc[mt][ntl]);
      }
    __syncthreads();      // eT reads done before zb overwrite
#pragma unroll
    for (int ntl = 0; ntl < 2; ++ntl) {
      int ch = w*32 + ntl*16 + p;
#pragma unroll
      for (int mt = 0; mt < 4; ++mt)
#pragma unroll
        for (int r = 0; r < 4; ++r) {
          float v = acc[mt][ntl][r];
          ss[ntl] += v; ss2[ntl] += v*v;
          zb[(mt*16 + q*4 + r)*ZSB + ch] = f2bf(v);
        }
    }
    __syncthreads();
#pragma unroll
    for (int it = 0; it < 4; ++it) {
      int pos = (t>>4) + it*16;
      int c8 = (t & 15)*8;
      *(u16x8*)&xb[xb_t(T) + pos*NO + c8] = *(const u16x8*)&zb[pos*ZSB + c8];
    }
  }
#pragma unroll
  for (int ntl = 0; ntl < 2; ++ntl) {
    float v = ss[ntl], v2 = ss2[ntl];
    v += __shfl_xor(v, 16); v += __shfl_xor(v, 32);
    v2 += __shfl_xor(v2, 16); v2 += __shfl_xor(v2, 32);
    if (q == 0) {
      int ch = w*32 + ntl*16 + p;
      part[((size_t)blk*NO + ch)*2 + 0] = v;
      part[((size_t)blk*NO + ch)*2 + 1] = v2;
    }
  }
}

// ---------------- x1 = relu(bn1(z1))*wgt (in place in xb) + down0 partials ----------------
__global__ __launch_bounds__(256,4) void k_x1(const float* __restrict__ knn_xyz,
                                              const float* __restrict__ lc_xyz,
                                              const float* __restrict__ wd,
                                              const float* __restrict__ bd,
                                              unsigned short* __restrict__ xb,
                                              const float* __restrict__ wsc,
                                              const float* __restrict__ bn1_stat,
                                              float* __restrict__ part) {
  __shared__ __align__(16) unsigned short xT[64*XS];
  __shared__ float s_wgt4[TPW*64];
  int t = threadIdx.x, blk = blockIdx.x;
  int lane = t & 63, w = t >> 6;
  int p = lane & 15, q = lane >> 4;
  int pos0 = t >> 4, ch8 = (t & 15)*8, oct = t & 15;

  short8v wfd[4];
#pragma unroll
  for (int ks = 0; ks < 4; ++ks) {
    short8v f;
#pragma unroll
    for (int j = 0; j < 8; ++j) f[j] = (short)f2bf(wd[(w*16+p)*NO + ks*32 + q*8 + j]);
    wfd[ks] = f;
  }
  float sc[8], sh[8];
#pragma unroll
  for (int e = 0; e < 8; ++e) { sc[e] = bn1_stat[(ch8+e)*2]; sh[e] = bn1_stat[(ch8+e)*2+1]; }
  float bdv = bd[w*16 + p];
  float inv_std = 1.0f / wsc[0];

  // gauss weights for all TPW tiles in one shot (t -> tile t>>6, pos t&63)
  {
    int gi4 = t >> 6, pp = t & 63;
    int bg0 = (blk*TPW + gi4)*2;
    const float* kx = knn_xyz + ((size_t)bg0*NK + pp)*3;
    const float* lc = lc_xyz + ((size_t)bg0 + (pp>>5))*3;
    float d2 = 0.f;
#pragma unroll
    for (int d = 0; d < 3; ++d) { float r = (kx[d]-lc[d])*inv_std - lc[d]; d2 += r*r; }
    s_wgt4[t] = expf(-sqrtf(d2)*0.5f);
  }

  float ss = 0.f, ss2 = 0.f;

  for (int gi = 0; gi < TPW; ++gi) {
    int T = blk*TPW + gi;
    __syncthreads();     // s_wgt4 ready (gi=0) / prev xT reads done
    const unsigned short* s = xb + xb_t(T);
    unsigned short* dst = xb + xb_t(T);
    u16x8 v0 = *(const u16x8*)&s[(pos0 +  0)*NO + ch8];
    u16x8 v1 = *(const u16x8*)&s[(pos0 + 16)*NO + ch8];
    u16x8 v2 = *(const u16x8*)&s[(pos0 + 32)*NO + ch8];
    u16x8 v3 = *(const u16x8*)&s[(pos0 + 48)*NO + ch8];
#define XF(NV, POFF) { int pos = pos0 + POFF;                                   \
      float wg = s_wgt4[gi*64 + pos]; u16x8 ov;                                 \
      _Pragma("unroll") for (int e = 0; e < 8; ++e) {                           \
        float v = fmaxf(bf2f(NV[e])*sc[e] + sh[e], 0.f) * wg; ov[e] = f2bf(v); }\
      *(u16x8*)&xT[pos*XS + ((oct ^ ((pos>>2)&7))<<3)] = ov;                    \
      *(u16x8*)&dst[pos*NO + ch8] = ov; }
    XF(v0, 0) XF(v1, 16) XF(v2, 32) XF(v3, 48)
#undef XF
    __syncthreads();     // xT visible
    f32x4 acc[4];
#pragma unroll
    for (int mt = 0; mt < 4; ++mt) acc[mt] = (f32x4){0.f,0.f,0.f,0.f};
#pragma unroll
    for (int ks = 0; ks < 4; ++ks)
#pragma unroll
      for (int mt = 0; mt < 4; ++mt) {
        int pos = mt*16 + p;
        short8v a = *(const short8v*)&xT[pos*XS + (((ks*4+q) ^ ((pos>>2)&7))<<3)];
        acc[mt] = MFMA(a, wfd[ks], acc[mt]);
      }
#pragma unroll
    for (int mt = 0; mt < 4; ++mt)
#pragma unroll
      for (int r = 0; r < 4; ++r) { float v = acc[mt][r] + bdv; ss += v; ss2 += v*v; }
  }
  ss += __shfl_xor(ss, 16); ss += __shfl_xor(ss, 32);
  ss2 += __shfl_xor(ss2, 16); ss2 += __shfl_xor(ss2, 32);
  if (q == 0) {
    part[((size_t)blk*NM + w*16 + p)*2 + 0] = ss;
    part[((size_t)blk*NM + w*16 + p)*2 + 1] = ss2;
  }
}

// ---------------- pass B: down+up recompute (ping-pong xT, staged-ahead), u_pre partials ----------------
__global__ __launch_bounds__(256,4) void k_bstat(const unsigned short* __restrict__ xb,
                                                 const float* __restrict__ wd,
                                                 const float* __restrict__ bd,
                                                 const float* __restrict__ wu,
                                                 const float* __restrict__ bu,
                                                 const float* __restrict__ bnd_stat,
                                                 float* __restrict__ part) {
  __shared__ __align__(16) unsigned short xTa[64*XS], xTb[64*XS];
  __shared__ __align__(16) unsigned short hT[64*HS];
  __shared__ float s_bu[NO];
  int t = threadIdx.x, blk = blockIdx.x;
  int lane = t & 63, w = t >> 6;
  int p = lane & 15, q = lane >> 4;
  int pos0 = t >> 4, ch8 = (t & 15)*8, oct = t & 15;

  short8v wfd[4];
#pragma unroll
  for (int ks = 0; ks < 4; ++ks) {
    short8v f;
#pragma unroll
    for (int j = 0; j < 8; ++j) f[j] = (short)f2bf(wd[(w*16+p)*NO + ks*32 + q*8 + j]);
    wfd[ks] = f;
  }
  short8v wfu[2][2];
#pragma unroll
  for (int ntl = 0; ntl < 2; ++ntl)
#pragma unroll
    for (int ks = 0; ks < 2; ++ks) {
      short8v f;
#pragma unroll
      for (int j = 0; j < 8; ++j) f[j] = (short)f2bf(wu[(w*32+ntl*16+p)*NM + ks*32 + q*8 + j]);
      wfu[ntl][ks] = f;
    }
  for (int i = t; i < NO; i += 256) s_bu[i] = bu[i];
  float c1 = bnd_stat[(w*16+p)*2];
  float c0 = bd[w*16+p]*c1 + bnd_stat[(w*16+p)*2+1];

  float ss[2] = {0.f,0.f}, ss2[2] = {0.f,0.f};

#define STG(DST, SRC) { \
    u16x8 v0 = *(const u16x8*)&(SRC)[(pos0 +  0)*NO + ch8]; \
    u16x8 v1 = *(const u16x8*)&(SRC)[(pos0 + 16)*NO + ch8]; \
    u16x8 v2 = *(const u16x8*)&(SRC)[(pos0 + 32)*NO + ch8]; \
    u16x8 v3 = *(const u16x8*)&(SRC)[(pos0 + 48)*NO + ch8]; \
    *(u16x8*)&(DST)[(pos0+ 0)*XS + ((oct ^ (((pos0+ 0)>>2)&7))<<3)] = v0; \
    *(u16x8*)&(DST)[(pos0+16)*XS + ((oct ^ (((pos0+16)>>2)&7))<<3)] = v1; \
    *(u16x8*)&(DST)[(pos0+32)*XS + ((oct ^ (((pos0+32)>>2)&7))<<3)] = v2; \
    *(u16x8*)&(DST)[(pos0+48)*XS + ((oct ^ (((pos0+48)>>2)&7))<<3)] = v3; }

  // prologue: stage tile 0
  STG(xTa, xb + xb_t(blk*TPW))
  __syncthreads();

#pragma unroll
  for (int gi = 0; gi < TPW; ++gi) {
    unsigned short* xT  = (gi & 1) ? xTb : xTa;
    unsigned short* xTn = (gi & 1) ? xTa : xTb;
    // --- phase 1: prefetch loads (early) + down-MFMA + prefetch ds_writes (late)
    u16x8 n0, n1, n2, n3;
    if (gi + 1 < TPW) {
      const unsigned short* s = xb + xb_t(blk*TPW + gi + 1);
      n0 = *(const u16x8*)&s[(pos0 +  0)*NO + ch8];
      n1 = *(const u16x8*)&s[(pos0 + 16)*NO + ch8];
      n2 = *(const u16x8*)&s[(pos0 + 32)*NO + ch8];
      n3 = *(const u16x8*)&s[(pos0 + 48)*NO + ch8];
    }
    {
      f32x4 dacc[4];
#pragma unroll
      for (int mt = 0; mt < 4; ++mt) dacc[mt] = (f32x4){0.f,0.f,0.f,0.f};
#pragma unroll
      for (int ks = 0; ks < 4; ++ks)
#pragma unroll
        for (int mt = 0; mt < 4; ++mt) {
          int pos = mt*16 + p;
          short8v a = *(const short8v*)&xT[pos*XS + (((ks*4+q) ^ ((pos>>2)&7))<<3)];
          dacc[mt] = MFMA(a, wfd[ks], dacc[mt]);
        }
      int ch = w*16 + p;
#pragma unroll
      for (int mt = 0; mt < 4; ++mt)
#pragma unroll
        for (int r = 0; r < 4; ++r) {
          int pos = mt*16 + q*4 + r;
          hT[pos*HS + swzo(ch, pos)] = f2bf(fmaxf(dacc[mt][r]*c1 + c0, 0.f));
        }
    }
    if (gi + 1 < TPW) {
      *(u16x8*)&xTn[(pos0+ 0)*XS + ((oct ^ (((pos0+ 0)>>2)&7))<<3)] = n0;
      *(u16x8*)&xTn[(pos0+16)*XS + ((oct ^ (((pos0+16)>>2)&7))<<3)] = n1;
      *(u16x8*)&xTn[(pos0+32)*XS + ((oct ^ (((pos0+32)>>2)&7))<<3)] = n2;
      *(u16x8*)&xTn[(pos0+48)*XS + ((oct ^ (((pos0+48)>>2)&7))<<3)] = n3;
    }
    __syncthreads();
    // --- phase 2: up-MFMA + stats
    {
      f32x4 uacc[4][2];
#pragma unroll
      for (int mt = 0; mt < 4; ++mt)
#pragma unroll
        for (int ntl = 0; ntl < 2; ++ntl) uacc[mt][ntl] = (f32x4){0.f,0.f,0.f,0.f};
#pragma unroll
      for (int ks = 0; ks < 2; ++ks)
#pragma unroll
        for (int mt = 0; mt < 4; ++mt) {
          int pos = mt*16 + p;
          short8v a = *(const short8v*)&hT[pos*HS + (((ks*4+q) ^ ((pos>>2)&7))<<3)];
#pragma unroll
          for (int ntl = 0; ntl < 2; ++ntl) uacc[mt][ntl] = MFMA(a, wfu[ntl][ks], uacc[mt][ntl]);
        }
#pragma unroll
      for (int ntl = 0; ntl < 2; ++ntl) {
        float buv = s_bu[w*32 + ntl*16 + p];
#pragma unroll
        for (int mt = 0; mt < 4; ++mt)
#pragma unroll
          for (int r = 0; r < 4; ++r) { float v = uacc[mt][ntl][r] + buv; ss[ntl] += v; ss2[ntl] += v*v; }
      }
    }
    __syncthreads();   // hT free for next tile; xTn ready
  }
#undef STG
#pragma unroll
  for (int ntl = 0; ntl < 2; ++ntl) {
    float v = ss[ntl], v2 = ss2[ntl];
    v += __shfl_xor(v, 16); v += __shfl_xor(v, 32);
    v2 += __shfl_xor(v2, 16); v2 += __shfl_xor(v2, 32);
    if (q == 0) {
      int ch = w*32 + ntl*16 + p;
      part[((size_t)blk*NO + ch)*2 + 0] = v;
      part[((size_t)blk*NO + ch)*2 + 1] = v2;
    }
  }
}

// ---------------- pass C: full block + residual (ping-pong xT, staged-ahead) ----------------
__global__ __launch_bounds__(256,4) void k_bfin(unsigned short* __restrict__ xb,
                                                float* __restrict__ out,
                                                const float* __restrict__ wd,
                                                const float* __restrict__ bd,
                                                const float* __restrict__ wu,
                                                const float* __restrict__ bu,
                                                const float* __restrict__ bnd_stat,
                                                const float* __restrict__ bnu_stat,
                                                const float* __restrict__ wdn,
                                                const float* __restrict__ bdn,
                                                float* __restrict__ part,
                                                int do_next) {
  __shared__ __align__(16) unsigned short xTa[64*XS], xTb[64*XS];
  __shared__ __align__(16) unsigned short hT[64*HS];
  __shared__ float s_u1[NO], s_u0[NO];
  int t = threadIdx.x, blk = blockIdx.x;
  int lane = t & 63, w = t >> 6;
  int p = lane & 15, q = lane >> 4;
  int pos0 = t >> 4, ch8 = (t & 15)*8, oct = t & 15;

  short8v wfd[4];
#pragma unroll
  for (int ks = 0; ks < 4; ++ks) {
    short8v f;
#pragma unroll
    for (int j = 0; j < 8; ++j) f[j] = (short)f2bf(wd[(w*16+p)*NO + ks*32 + q*8 + j]);
    wfd[ks] = f;
  }
  short8v wfu[2][2];
#pragma unroll
  for (int ntl = 0; ntl < 2; ++ntl)
#pragma unroll
    for (int ks = 0; ks < 2; ++ks) {
      short8v f;
#pragma unroll
      for (int j = 0; j < 8; ++j) f[j] = (short)f2bf(wu[(w*32+ntl*16+p)*NM + ks*32 + q*8 + j]);
      wfu[ntl][ks] = f;
    }
  short8v wfn[4];
  if (do_next) {
#pragma unroll
    for (int ks = 0; ks < 4; ++ks) {
      short8v f;
#pragma unroll
      for (int j = 0; j < 8; ++j) f[j] = (short)f2bf(wdn[(w*16+p)*NO + ks*32 + q*8 + j]);
      wfn[ks] = f;
    }
  }
  float c1 = bnd_stat[(w*16+p)*2];
  float c0 = bd[w*16+p]*c1 + bnd_stat[(w*16+p)*2+1];
  float bdnv = do_next ? bdn[w*16+p] : 0.f;
  for (int i = t; i < NO; i += 256) {
    float scv = bnu_stat[i*2];
    s_u1[i] = scv; s_u0[i] = bu[i]*scv + bnu_stat[i*2+1];
  }

  float ss = 0.f, ss2 = 0.f;

  // prologue: stage tile 0 into xTa
  {
    const unsigned short* s = xb + xb_t(blk*TPW);
    u16x8 v0 = *(const u16x8*)&s[(pos0 +  0)*NO + ch8];
    u16x8 v1 = *(const u16x8*)&s[(pos0 + 16)*NO + ch8];
    u16x8 v2 = *(const u16x8*)&s[(pos0 + 32)*NO + ch8];
    u16x8 v3 = *(const u16x8*)&s[(pos0 + 48)*NO + ch8];
    *(u16x8*)&xTa[(pos0+ 0)*XS + ((oct ^ (((pos0+ 0)>>2)&7))<<3)] = v0;
    *(u16x8*)&xTa[(pos0+16)*XS + ((oct ^ (((pos0+16)>>2)&7))<<3)] = v1;
    *(u16x8*)&xTa[(pos0+32)*XS + ((oct ^ (((pos0+32)>>2)&7))<<3)] = v2;
    *(u16x8*)&xTa[(pos0+48)*XS + ((oct ^ (((pos0+48)>>2)&7))<<3)] = v3;
  }
  __syncthreads();

#pragma unroll
  for (int gi = 0; gi < TPW; ++gi) {
    int T = blk*TPW + gi;
    int bg0 = T*2;
    int b = bg0 >> 11, g0 = bg0 & (NG-1);
    unsigned short* xT  = (gi & 1) ? xTb : xTa;
    unsigned short* xTn = (gi & 1) ? xTa : xTb;
    // --- phase 1: prefetch loads + down-MFMA + prefetch ds_writes
    u16x8 n0, n1, n2, n3;
    if (gi + 1 < TPW) {
      const unsigned short* s = xb + xb_t(T + 1);
      n0 = *(const u16x8*)&s[(pos0 +  0)*NO + ch8];
      n1 = *(const u16x8*)&s[(pos0 + 16)*NO + ch8];
      n2 = *(const u16x8*)&s[(pos0 + 32)*NO + ch8];
      n3 = *(const u16x8*)&s[(pos0 + 48)*NO + ch8];
    }
    {
      f32x4 dacc[4];
#pragma unroll
      for (int mt = 0; mt < 4; ++mt) dacc[mt] = (f32x4){0.f,0.f,0.f,0.f};
#pragma unroll
      for (int ks = 0; ks < 4; ++ks)
#pragma unroll
        for (int mt = 0; mt < 4; ++mt) {
          int pos = mt*16 + p;
          short8v a = *(const short8v*)&xT[pos*XS + (((ks*4+q) ^ ((pos>>2)&7))<<3)];
          dacc[mt] = MFMA(a, wfd[ks], dacc[mt]);
        }
      int ch = w*16 + p;
#pragma unroll
      for (int mt = 0; mt < 4; ++mt)
#pragma unroll
        for (int r = 0; r < 4; ++r) {
          int pos = mt*16 + q*4 + r;
          hT[pos*HS + swzo(ch, pos)] = f2bf(fmaxf(dacc[mt][r]*c1 + c0, 0.f));
        }
    }
    if (gi + 1 < TPW) {
      *(u16x8*)&xTn[(pos0+ 0)*XS + ((oct ^ (((pos0+ 0)>>2)&7))<<3)] = n0;
      *(u16x8*)&xTn[(pos0+16)*XS + ((oct ^ (((pos0+16)>>2)&7))<<3)] = n1;
      *(u16x8*)&xTn[(pos0+32)*XS + ((oct ^ (((pos0+32)>>2)&7))<<3)] = n2;
      *(u16x8*)&xTn[(pos0+48)*XS + ((oct ^ (((pos0+48)>>2)&7))<<3)] = n3;
    }
    __syncthreads();
    // --- phase 2: up-MFMA + residual (per-lane exclusive xT RMW in fragment layout)
    {
      f32x4 uacc[4][2];
#pragma unroll
      for (int mt = 0; mt < 4; ++mt)
#pragma unroll
        for (int ntl = 0; ntl < 2; ++ntl) uacc[mt][ntl] = (f32x4){0.f,0.f,0.f,0.f};
#pragma unroll
      for (int ks = 0; ks < 2; ++ks)
#pragma unroll
        for (int mt = 0; mt < 4; ++mt) {
          int pos = mt*16 + p;
          short8v a = *(const short8v*)&hT[pos*HS + (((ks*4+q) ^ ((pos>>2)&7))<<3)];
#pragma unroll
          for (int ntl = 0; ntl < 2; ++ntl) uacc[mt][ntl] = MFMA(a, wfu[ntl][ks], uacc[mt][ntl]);
        }
#pragma unroll
      for (int ntl = 0; ntl < 2; ++ntl) {
        int ch = w*32 + ntl*16 + p;
        float u1 = s_u1[ch], u0 = s_u0[ch];
#pragma unroll
        for (int mt = 0; mt < 4; ++mt)
#pragma unroll
          for (int r = 0; r < 4; ++r) {
            int pos = mt*16 + q*4 + r;
            int off = pos*XS + swzo(ch, pos);
            float u = uacc[mt][ntl][r]*u1 + u0;
            float xn = fmaxf(u + bf2f(xT[off]), 0.f);
            xT[off] = f2bf(xn);
          }
      }
    }
    __syncthreads();   // xT = new-x complete
    // --- phase 3: writeback (+ next-down stats) from xT
    if (do_next) {
      unsigned short* dst = xb + xb_t(T);
#pragma unroll
      for (int it = 0; it < 4; ++it) {
        int pos = pos0 + it*16;
        u16x8 ov = *(const u16x8*)&xT[pos*XS + ((oct ^ ((pos>>2)&7))<<3)];
        *(u16x8*)&dst[pos*NO + ch8] = ov;
      }
      f32x4 nacc[4];
#pragma unroll
      for (int mt = 0; mt < 4; ++mt) nacc[mt] = (f32x4){0.f,0.f,0.f,0.f};
#pragma unroll
      for (int ks = 0; ks < 4; ++ks)
#pragma unroll
        for (int mt = 0; mt < 4; ++mt) {
          int pos = mt*16 + p;
          short8v a = *(const short8v*)&xT[pos*XS + (((ks*4+q) ^ ((pos>>2)&7))<<3)];
          nacc[mt] = MFMA(a, wfn[ks], nacc[mt]);
        }
#pragma unroll
      for (int mt = 0; mt < 4; ++mt)
#pragma unroll
        for (int r = 0; r < 4; ++r) { float v = nacc[mt][r] + bdnv; ss += v; ss2 += v*v; }
    } else {
      // final f32 output
#pragma unroll
      for (int it = 0; it < 8; ++it) {
        int i = t + it*256;
        int ch = i >> 4, p4 = (i & 15)*4;
        f32x4 o;
#pragma unroll
        for (int r = 0; r < 4; ++r) o[r] = bf2f(xT[(p4+r)*XS + swzo(ch, p4+r)]);
        *(f32x4*)&out[(((size_t)b*NO + ch)*NG + g0)*NK + p4] = o;
      }
    }
    __syncthreads();   // xT free for gi+2's staging
  }
  if (do_next) {
    ss += __shfl_xor(ss, 16); ss += __shfl_xor(ss, 32);
    ss2 += __shfl_xor(ss2, 16); ss2 += __shfl_xor(ss2, 32);
    if (q == 0) {
      part[((size_t)blk*NM + w*16 + p)*2 + 0] = ss;
      part[((size_t)blk*NM + w*16 + p)*2 + 1] = ss2;
    }
  }
}

extern "C" void kernel_launch(void* const* d_in, const int* in_sizes, int n_in,
                              void* d_out, int out_size, void* d_ws, size_t ws_size,
                              hipStream_t stream) {
  const float* lc_xyz   = (const float*)d_in[0];
  const float* lc_feat  = (const float*)d_in[1];
  const float* knn_xyz  = (const float*)d_in[2];
  const float* knn_feat = (const float*)d_in[3];
  const float* w1       = (const float*)d_in[4];
  const float* bn1_g    = (const float*)d_in[5];
  const float* bn1_b    = (const float*)d_in[6];
  const float* wd       = (const float*)d_in[7];
  const float* bd       = (const float*)d_in[8];
  const float* dn_g     = (const float*)d_in[9];
  const float* dn_b     = (const float*)d_in[10];
  const float* wu       = (const float*)d_in[11];
  const float* bu       = (const float*)d_in[12];
  const float* up_g     = (const float*)d_in[13];
  const float* up_b     = (const float*)d_in[14];
  float* out = (float*)d_out;
  float* ws  = (float*)d_ws;
  unsigned short* xb = (unsigned short*)((char*)d_ws + XB_BYTE_OFF);

  k_std_part<<<256, 256, 0, stream>>>(knn_xyz, lc_xyz, ws + OFF_STD_PART);
  k_std_fin<<<1, 256, 0, stream>>>(ws + OFF_STD_PART, ws + OFF_STD);

  k_z1<<<NWGT, 256, 0, stream>>>(knn_feat, lc_feat, w1, xb, ws + OFF_PART);
  k_fin_bn<<<128, 256, 0, stream>>>(ws + OFF_PART, 128, NWGT, bn1_g, bn1_b, ws + OFF_STATA);

  k_x1<<<NWGT, 256, 0, stream>>>(knn_xyz, lc_xyz, wd, bd, xb, ws + OFF_STD,
                                 ws + OFF_STATA, ws + OFF_PART);
  k_fin_bn<<<64, 256, 0, stream>>>(ws + OFF_PART, 64, NWGT, dn_g, dn_b, ws + OFF_STATB);

  k_bstat<<<NWGT, 256, 0, stream>>>(xb, wd, bd, wu, bu, ws + OFF_STATB, ws + OFF_PART);
  k_fin_bn<<<128, 256, 0, stream>>>(ws + OFF_PART, 128, NWGT, up_g, up_b, ws + OFF_STATC);

  k_bfin<<<NWGT, 256, 0, stream>>>(xb, out, wd, bd, wu, bu, ws + OFF_STATB, ws + OFF_STATC,
                                   wd + 64*128, bd + 64, ws + OFF_PART, 1);
  k_fin_bn<<<64, 256, 0, stream>>>(ws + OFF_PART, 64, NWGT, dn_g + 64, dn_b + 64, ws + OFF_STATB);

  k_bstat<<<NWGT, 256, 0, stream>>>(xb, wd + 64*128, bd + 64, wu + 128*64, bu + 128,
                                    ws + OFF_STATB, ws + OFF_PART);
  k_fin_bn<<<128, 256, 0, stream>>>(ws + OFF_PART, 128, NWGT, up_g + 128, up_b + 128, ws + OFF_STATC);

  k_bfin<<<NWGT, 256, 0, stream>>>(xb, out, wd + 64*128, bd + 64, wu + 128*64, bu + 128,
                                   ws + OFF_STATB, ws + OFF_STATC,
                                   (const float*)nullptr, (const float*)nullptr,
                                   ws + OFF_PART, 0);
}

// Round 13
// 451.652 us; speedup vs baseline: 1.7872x; 1.0070x over previous
//
#include <hip/hip_runtime.h>
#include <math.h>

#define NB 8
#define NG 2048
#define NK 32
#define NO 128
#define NM 64
#define NC 131
#define NPT (NB*NG*NK)      // 524288 positions
#define NWGT 2048           // blocks for tile passes
#define TPW 4               // tiles (of 64 positions) per workgroup

// LDS row strides (bf16 elements); octet count multiple of 8 so the
// (c>>3)^((pos>>2)&7) swizzle is closed within each row.
#define XS 136              // xT (K=128 -> 16 octets + pad)
#define ES 192              // eT (K padded 131->160 -> 24 octets)
#define HS 72               // hT (K=64 -> 8 octets + pad)
#define ZSB 136             // zb stride [pos][ch] (128 + 8 pad)

// workspace layout: floats at small offsets, xb (tile-major bf16) at +8 MB.
#define OFF_STD_PART 0
#define OFF_STD      512
#define OFF_STATA    1024
#define OFF_STATB    1536
#define OFF_STATC    2048
#define OFF_PART     4096
#define XB_BYTE_OFF  (8u << 20)

typedef __attribute__((ext_vector_type(8))) short short8v;
typedef __attribute__((ext_vector_type(4))) float f32x4;
typedef __attribute__((ext_vector_type(8))) unsigned short u16x8;

#define MFMA(a,b,c) __builtin_amdgcn_mfma_f32_16x16x32_bf16(a,b,c,0,0,0)

__device__ inline unsigned short f2bf(float f) {
  unsigned u = __builtin_bit_cast(unsigned, f);
  unsigned r = u + 0x7fffu + ((u >> 16) & 1u);
  return (unsigned short)(r >> 16);
}
__device__ inline float bf2f(unsigned short h) {
  unsigned u = ((unsigned)h) << 16;
  return __builtin_bit_cast(float, u);
}
__device__ inline int swzo(int ch, int pos) {
  return (((ch >> 3) ^ ((pos >> 2) & 7)) << 3) | (ch & 7);
}

// xb: tile-major bf16 activations in d_ws: [T][pos(64)][ch(128)]
__device__ inline size_t xb_t(int T) { return (size_t)T * (64*NO); }

// ---------------- std of rel0 (ddof=1) ----------------
__global__ __launch_bounds__(256) void k_std_part(const float* __restrict__ knn_xyz,
                                                  const float* __restrict__ lc_xyz,
                                                  float* __restrict__ part) {
  int t = threadIdx.x, blk = blockIdx.x;
  int gsz = gridDim.x * blockDim.x;
  float s = 0.f, s2 = 0.f;
  for (int i = blk*256 + t; i < NPT*3; i += gsz) {
    int d = i % 3;
    int pk = i / 3;
    int bg = pk / NK;
    float r = knn_xyz[i] - lc_xyz[bg*3 + d];
    s += r; s2 += r*r;
  }
  __shared__ float ls[256], ls2[256];
  ls[t] = s; ls2[t] = s2; __syncthreads();
  for (int off = 128; off >= 1; off >>= 1) {
    if (t < off) { ls[t] += ls[t+off]; ls2[t] += ls2[t+off]; }
    __syncthreads();
  }
  if (t == 0) { part[blk*2] = ls[0]; part[blk*2+1] = ls2[0]; }
}

__global__ __launch_bounds__(256) void k_std_fin(const float* __restrict__ part,
                                                 float* __restrict__ wsc) {
  int t = threadIdx.x;
  __shared__ float ls[256], ls2[256];
  ls[t] = part[t*2]; ls2[t] = part[t*2+1]; __syncthreads();
  for (int off = 128; off >= 1; off >>= 1) {
    if (t < off) { ls[t] += ls[t+off]; ls2[t] += ls2[t+off]; }
    __syncthreads();
  }
  if (t == 0) {
    double S = ls[0], S2 = ls2[0];
    double n = (double)NPT * 3.0;
    double var = (S2 - S*S/n) / (n - 1.0);
    wsc[0] = (float)(sqrt(var) + 1e-5);
  }
}

// ---------------- BN finalize ----------------
__global__ __launch_bounds__(256) void k_fin_bn(const float* __restrict__ part, int C, int nrows,
                                                const float* __restrict__ gamma,
                                                const float* __restrict__ beta,
                                                float* __restrict__ stat) {
  int o = blockIdx.x, t = threadIdx.x;
  float s = 0.f, s2 = 0.f;
  for (int r = t; r < nrows; r += 256) {
    s  += part[((size_t)r*C + o)*2 + 0];
    s2 += part[((size_t)r*C + o)*2 + 1];
  }
  __shared__ float ls[256], ls2[256];
  ls[t] = s; ls2[t] = s2; __syncthreads();
  for (int off = 128; off >= 1; off >>= 1) {
    if (t < off) { ls[t] += ls[t+off]; ls2[t] += ls2[t+off]; }
    __syncthreads();
  }
  if (t == 0) {
    float n = (float)NPT;
    float mean = ls[0] / n;
    float var  = ls2[0] / n - mean*mean;
    float sc = gamma[o] * rsqrtf(var + 1e-5f);
    stat[o*2]   = sc;
    stat[o*2+1] = beta[o] - mean*sc;
  }
}

// ---------------- z1 = expanded @ W1^T -> xb [pos][ch], BN1 partials ----------------
__global__ __launch_bounds__(256,4) void k_z1(const float* __restrict__ knn_feat,
                                              const float* __restrict__ lc_feat,
                                              const float* __restrict__ w1,
                                              unsigned short* __restrict__ xb,
                                              float* __restrict__ part) {
  __shared__ __align__(16) unsigned short shmem[64*ES];  // 24576 B; overlaid eT / zb
  unsigned short* eT = shmem;
  unsigned short* zb = shmem;   // [pos][ZSB]
  int t = threadIdx.x, blk = blockIdx.x;
  int lane = t & 63, w = t >> 6;
  int p = lane & 15, q = lane >> 4;

  short8v wf[2][5];
#pragma unroll
  for (int ntl = 0; ntl < 2; ++ntl)
#pragma unroll
    for (int ks = 0; ks < 5; ++ks) {
      int row = w*32 + ntl*16 + p;
      int kb = ks*32 + q*8;
      short8v f;
#pragma unroll
      for (int j = 0; j < 8; ++j) {
        int k = kb + j;
        f[j] = (short)((k < NC) ? f2bf(w1[row*NC + k]) : 0);
      }
      wf[ntl][ks] = f;
    }

  float ss[2] = {0.f, 0.f}, ss2[2] = {0.f, 0.f};

  for (int gi = 0; gi < TPW; ++gi) {
    int T = blk*TPW + gi;
    int bg0 = T*2;
    __syncthreads();      // protects eT write vs previous zb reads
    const float* kf = knn_feat + (size_t)bg0*NK*67;
    for (int i = t; i < 64*67; i += 256) {
      int pos = i/67, c = i - pos*67;
      eT[pos*ES + swzo(c, pos)] = f2bf(kf[i]);
    }
    const float* lf = lc_feat + (size_t)bg0*64;
    for (int i = t; i < 64*64; i += 256) {
      int pos = i >> 6, c = i & 63;
      eT[pos*ES + swzo(67 + c, pos)] = f2bf(lf[(pos>>5)*64 + c]);
    }
    for (int i = t; i < 64*32; i += 256) {
      int pos = i >> 5, c = 131 + (i & 31);
      if (c < 160) eT[pos*ES + swzo(c, pos)] = 0;
    }
    __syncthreads();

    f32x4 acc[4][2];
#pragma unroll
    for (int mt = 0; mt < 4; ++mt)
#pragma unroll
      for (int ntl = 0; ntl < 2; ++ntl) acc[mt][ntl] = (f32x4){0.f,0.f,0.f,0.f};
#pragma unroll
    for (int ks = 0; ks < 5; ++ks)
#pragma unroll
      for (int mt = 0; mt < 4; ++mt) {
        int pos = mt*16 + p;
        short8v a = *(const short8v*)&eT[pos*ES + (((ks*4+q) ^ ((pos>>2)&7))<<3)];
#pragma unroll
        for (int ntl = 0; ntl < 2; ++ntl) acc[mt][ntl] = MFMA(a, wf[ntl][ks], acc[mt][ntl]);
      }
    __syncthreads();      // eT reads done before zb overwrite
#pragma unroll
    for (int ntl = 0; ntl < 2; ++ntl) {
      int ch = w*32 + ntl*16 + p;
#pragma unroll
      for (int mt = 0; mt < 4; ++mt)
#pragma unroll
        for (int r = 0; r < 4; ++r) {
          float v = acc[mt][ntl][r];
          ss[ntl] += v; ss2[ntl] += v*v;
          zb[(mt*16 + q*4 + r)*ZSB + ch] = f2bf(v);
        }
    }
    __syncthreads();
#pragma unroll
    for (int it = 0; it < 4; ++it) {
      int pos = (t>>4) + it*16;
      int c8 = (t & 15)*8;
      *(u16x8*)&xb[xb_t(T) + pos*NO + c8] = *(const u16x8*)&zb[pos*ZSB + c8];
    }
  }
#pragma unroll
  for (int ntl = 0; ntl < 2; ++ntl) {
    float v = ss[ntl], v2 = ss2[ntl];
    v += __shfl_xor(v, 16); v += __shfl_xor(v, 32);
    v2 += __shfl_xor(v2, 16); v2 += __shfl_xor(v2, 32);
    if (q == 0) {
      int ch = w*32 + ntl*16 + p;
      part[((size_t)blk*NO + ch)*2 + 0] = v;
      part[((size_t)blk*NO + ch)*2 + 1] = v2;
    }
  }
}

// ---------------- x1 = relu(bn1(z1))*wgt (ping-pong xT, staged-ahead) + down0 partials ----------------
__global__ __launch_bounds__(256,4) void k_x1(const float* __restrict__ knn_xyz,
                                              const float* __restrict__ lc_xyz,
                                              const float* __restrict__ wd,
                                              const float* __restrict__ bd,
                                              unsigned short* __restrict__ xb,
                                              const float* __restrict__ wsc,
                                              const float* __restrict__ bn1_stat,
                                              float* __restrict__ part) {
  __shared__ __align__(16) unsigned short xTa[64*XS], xTb[64*XS];
  __shared__ float s_wgt4[TPW*64];
  int t = threadIdx.x, blk = blockIdx.x;
  int lane = t & 63, w = t >> 6;
  int p = lane & 15, q = lane >> 4;
  int pos0 = t >> 4, ch8 = (t & 15)*8, oct = t & 15;

  short8v wfd[4];
#pragma unroll
  for (int ks = 0; ks < 4; ++ks) {
    short8v f;
#pragma unroll
    for (int j = 0; j < 8; ++j) f[j] = (short)f2bf(wd[(w*16+p)*NO + ks*32 + q*8 + j]);
    wfd[ks] = f;
  }
  float sc[8], sh[8];
#pragma unroll
  for (int e = 0; e < 8; ++e) { sc[e] = bn1_stat[(ch8+e)*2]; sh[e] = bn1_stat[(ch8+e)*2+1]; }
  float bdv = bd[w*16 + p];
  float inv_std = 1.0f / wsc[0];

  // gauss weights for all TPW tiles in one shot (t -> tile t>>6, pos t&63)
  {
    int gi4 = t >> 6, pp = t & 63;
    int bg0 = (blk*TPW + gi4)*2;
    const float* kx = knn_xyz + ((size_t)bg0*NK + pp)*3;
    const float* lc = lc_xyz + ((size_t)bg0 + (pp>>5))*3;
    float d2 = 0.f;
#pragma unroll
    for (int d = 0; d < 3; ++d) { float r = (kx[d]-lc[d])*inv_std - lc[d]; d2 += r*r; }
    s_wgt4[t] = expf(-sqrtf(d2)*0.5f);
  }

  // transform NV (raw tile gi's rows) -> xT dst + xb writeback
#define XF1(DSTL, NV, POFF, GIW, DSTG) { int pos = pos0 + POFF;                 \
    float wg = s_wgt4[(GIW)*64 + pos]; u16x8 ov;                                \
    _Pragma("unroll") for (int e = 0; e < 8; ++e) {                             \
      float v = fmaxf(bf2f(NV[e])*sc[e] + sh[e], 0.f) * wg; ov[e] = f2bf(v); }  \
    *(u16x8*)&(DSTL)[pos*XS + ((oct ^ ((pos>>2)&7))<<3)] = ov;                  \
    *(u16x8*)&(DSTG)[pos*NO + ch8] = ov; }

  // prologue: load tile 0, sync (wgt visible), transform -> xTa
  {
    const unsigned short* s = xb + xb_t(blk*TPW);
    u16x8 m0 = *(const u16x8*)&s[(pos0 +  0)*NO + ch8];
    u16x8 m1 = *(const u16x8*)&s[(pos0 + 16)*NO + ch8];
    u16x8 m2 = *(const u16x8*)&s[(pos0 + 32)*NO + ch8];
    u16x8 m3 = *(const u16x8*)&s[(pos0 + 48)*NO + ch8];
    __syncthreads();          // s_wgt4 visible
    unsigned short* dst = xb + xb_t(blk*TPW);
    XF1(xTa, m0,  0, 0, dst) XF1(xTa, m1, 16, 0, dst)
    XF1(xTa, m2, 32, 0, dst) XF1(xTa, m3, 48, 0, dst)
  }

  float ss = 0.f, ss2 = 0.f;

#pragma unroll
  for (int gi = 0; gi < TPW; ++gi) {
    int T = blk*TPW + gi;
    unsigned short* xT  = (gi & 1) ? xTb : xTa;
    unsigned short* xTn = (gi & 1) ? xTa : xTb;
    __syncthreads();          // xT (tile gi, transformed) visible
    // prefetch raw tile gi+1
    u16x8 n0, n1, n2, n3;
    if (gi + 1 < TPW) {
      const unsigned short* s = xb + xb_t(T + 1);
      n0 = *(const u16x8*)&s[(pos0 +  0)*NO + ch8];
      n1 = *(const u16x8*)&s[(pos0 + 16)*NO + ch8];
      n2 = *(const u16x8*)&s[(pos0 + 32)*NO + ch8];
      n3 = *(const u16x8*)&s[(pos0 + 48)*NO + ch8];
    }
    // down-MFMA on tile gi
    f32x4 acc[4];
#pragma unroll
    for (int mt = 0; mt < 4; ++mt) acc[mt] = (f32x4){0.f,0.f,0.f,0.f};
#pragma unroll
    for (int ks = 0; ks < 4; ++ks)
#pragma unroll
      for (int mt = 0; mt < 4; ++mt) {
        int pos = mt*16 + p;
        short8v a = *(const short8v*)&xT[pos*XS + (((ks*4+q) ^ ((pos>>2)&7))<<3)];
        acc[mt] = MFMA(a, wfd[ks], acc[mt]);
      }
#pragma unroll
    for (int mt = 0; mt < 4; ++mt)
#pragma unroll
      for (int r = 0; r < 4; ++r) { float v = acc[mt][r] + bdv; ss += v; ss2 += v*v; }
    // transform tile gi+1 -> xTn + xb writeback
    if (gi + 1 < TPW) {
      unsigned short* dst = xb + xb_t(T + 1);
      XF1(xTn, n0,  0, gi+1, dst) XF1(xTn, n1, 16, gi+1, dst)
      XF1(xTn, n2, 32, gi+1, dst) XF1(xTn, n3, 48, gi+1, dst)
    }
  }
#undef XF1
  ss += __shfl_xor(ss, 16); ss += __shfl_xor(ss, 32);
  ss2 += __shfl_xor(ss2, 16); ss2 += __shfl_xor(ss2, 32);
  if (q == 0) {
    part[((size_t)blk*NM + w*16 + p)*2 + 0] = ss;
    part[((size_t)blk*NM + w*16 + p)*2 + 1] = ss2;
  }
}

// ---------------- pass B: down+up recompute (ping-pong xT, staged-ahead), u_pre partials ----------------
__global__ __launch_bounds__(256,4) void k_bstat(const unsigned short* __restrict__ xb,
                                                 const float* __restrict__ wd,
                                                 const float* __restrict__ bd,
                                                 const float* __restrict__ wu,
                                                 const float* __restrict__ bu,
                                                 const float* __restrict__ bnd_stat,
                                                 float* __restrict__ part) {
  __shared__ __align__(16) unsigned short xTa[64*XS], xTb[64*XS];
  __shared__ __align__(16) unsigned short hT[64*HS];
  __shared__ float s_bu[NO];
  int t = threadIdx.x, blk = blockIdx.x;
  int lane = t & 63, w = t >> 6;
  int p = lane & 15, q = lane >> 4;
  int pos0 = t >> 4, ch8 = (t & 15)*8, oct = t & 15;

  short8v wfd[4];
#pragma unroll
  for (int ks = 0; ks < 4; ++ks) {
    short8v f;
#pragma unroll
    for (int j = 0; j < 8; ++j) f[j] = (short)f2bf(wd[(w*16+p)*NO + ks*32 + q*8 + j]);
    wfd[ks] = f;
  }
  short8v wfu[2][2];
#pragma unroll
  for (int ntl = 0; ntl < 2; ++ntl)
#pragma unroll
    for (int ks = 0; ks < 2; ++ks) {
      short8v f;
#pragma unroll
      for (int j = 0; j < 8; ++j) f[j] = (short)f2bf(wu[(w*32+ntl*16+p)*NM + ks*32 + q*8 + j]);
      wfu[ntl][ks] = f;
    }
  for (int i = t; i < NO; i += 256) s_bu[i] = bu[i];
  float c1 = bnd_stat[(w*16+p)*2];
  float c0 = bd[w*16+p]*c1 + bnd_stat[(w*16+p)*2+1];

  float ss[2] = {0.f,0.f}, ss2[2] = {0.f,0.f};

#define STG(DST, SRC) { \
    u16x8 v0 = *(const u16x8*)&(SRC)[(pos0 +  0)*NO + ch8]; \
    u16x8 v1 = *(const u16x8*)&(SRC)[(pos0 + 16)*NO + ch8]; \
    u16x8 v2 = *(const u16x8*)&(SRC)[(pos0 + 32)*NO + ch8]; \
    u16x8 v3 = *(const u16x8*)&(SRC)[(pos0 + 48)*NO + ch8]; \
    *(u16x8*)&(DST)[(pos0+ 0)*XS + ((oct ^ (((pos0+ 0)>>2)&7))<<3)] = v0; \
    *(u16x8*)&(DST)[(pos0+16)*XS + ((oct ^ (((pos0+16)>>2)&7))<<3)] = v1; \
    *(u16x8*)&(DST)[(pos0+32)*XS + ((oct ^ (((pos0+32)>>2)&7))<<3)] = v2; \
    *(u16x8*)&(DST)[(pos0+48)*XS + ((oct ^ (((pos0+48)>>2)&7))<<3)] = v3; }

  // prologue: stage tile 0
  STG(xTa, xb + xb_t(blk*TPW))
  __syncthreads();

#pragma unroll
  for (int gi = 0; gi < TPW; ++gi) {
    unsigned short* xT  = (gi & 1) ? xTb : xTa;
    unsigned short* xTn = (gi & 1) ? xTa : xTb;
    // --- phase 1: prefetch loads (early) + down-MFMA + prefetch ds_writes (late)
    u16x8 n0, n1, n2, n3;
    if (gi + 1 < TPW) {
      const unsigned short* s = xb + xb_t(blk*TPW + gi + 1);
      n0 = *(const u16x8*)&s[(pos0 +  0)*NO + ch8];
      n1 = *(const u16x8*)&s[(pos0 + 16)*NO + ch8];
      n2 = *(const u16x8*)&s[(pos0 + 32)*NO + ch8];
      n3 = *(const u16x8*)&s[(pos0 + 48)*NO + ch8];
    }
    {
      f32x4 dacc[4];
#pragma unroll
      for (int mt = 0; mt < 4; ++mt) dacc[mt] = (f32x4){0.f,0.f,0.f,0.f};
#pragma unroll
      for (int ks = 0; ks < 4; ++ks)
#pragma unroll
        for (int mt = 0; mt < 4; ++mt) {
          int pos = mt*16 + p;
          short8v a = *(const short8v*)&xT[pos*XS + (((ks*4+q) ^ ((pos>>2)&7))<<3)];
          dacc[mt] = MFMA(a, wfd[ks], dacc[mt]);
        }
      int ch = w*16 + p;
#pragma unroll
      for (int mt = 0; mt < 4; ++mt)
#pragma unroll
        for (int r = 0; r < 4; ++r) {
          int pos = mt*16 + q*4 + r;
          hT[pos*HS + swzo(ch, pos)] = f2bf(fmaxf(dacc[mt][r]*c1 + c0, 0.f));
        }
    }
    if (gi + 1 < TPW) {
      *(u16x8*)&xTn[(pos0+ 0)*XS + ((oct ^ (((pos0+ 0)>>2)&7))<<3)] = n0;
      *(u16x8*)&xTn[(pos0+16)*XS + ((oct ^ (((pos0+16)>>2)&7))<<3)] = n1;
      *(u16x8*)&xTn[(pos0+32)*XS + ((oct ^ (((pos0+32)>>2)&7))<<3)] = n2;
      *(u16x8*)&xTn[(pos0+48)*XS + ((oct ^ (((pos0+48)>>2)&7))<<3)] = n3;
    }
    __syncthreads();
    // --- phase 2: up-MFMA + stats
    {
      f32x4 uacc[4][2];
#pragma unroll
      for (int mt = 0; mt < 4; ++mt)
#pragma unroll
        for (int ntl = 0; ntl < 2; ++ntl) uacc[mt][ntl] = (f32x4){0.f,0.f,0.f,0.f};
#pragma unroll
      for (int ks = 0; ks < 2; ++ks)
#pragma unroll
        for (int mt = 0; mt < 4; ++mt) {
          int pos = mt*16 + p;
          short8v a = *(const short8v*)&hT[pos*HS + (((ks*4+q) ^ ((pos>>2)&7))<<3)];
#pragma unroll
          for (int ntl = 0; ntl < 2; ++ntl) uacc[mt][ntl] = MFMA(a, wfu[ntl][ks], uacc[mt][ntl]);
        }
#pragma unroll
      for (int ntl = 0; ntl < 2; ++ntl) {
        float buv = s_bu[w*32 + ntl*16 + p];
#pragma unroll
        for (int mt = 0; mt < 4; ++mt)
#pragma unroll
          for (int r = 0; r < 4; ++r) { float v = uacc[mt][ntl][r] + buv; ss[ntl] += v; ss2[ntl] += v*v; }
      }
    }
    __syncthreads();   // hT free for next tile; xTn ready
  }
#undef STG
#pragma unroll
  for (int ntl = 0; ntl < 2; ++ntl) {
    float v = ss[ntl], v2 = ss2[ntl];
    v += __shfl_xor(v, 16); v += __shfl_xor(v, 32);
    v2 += __shfl_xor(v2, 16); v2 += __shfl_xor(v2, 32);
    if (q == 0) {
      int ch = w*32 + ntl*16 + p;
      part[((size_t)blk*NO + ch)*2 + 0] = v;
      part[((size_t)blk*NO + ch)*2 + 1] = v2;
    }
  }
}

// ---------------- pass C: full block + residual (ping-pong xT, staged-ahead) ----------------
__global__ __launch_bounds__(256,4) void k_bfin(unsigned short* __restrict__ xb,
                                                float* __restrict__ out,
                                                const float* __restrict__ wd,
                                                const float* __restrict__ bd,
                                                const float* __restrict__ wu,
                                                const float* __restrict__ bu,
                                                const float* __restrict__ bnd_stat,
                                                const float* __restrict__ bnu_stat,
                                                const float* __restrict__ wdn,
                                                const float* __restrict__ bdn,
                                                float* __restrict__ part,
                                                int do_next) {
  __shared__ __align__(16) unsigned short xTa[64*XS], xTb[64*XS];
  __shared__ __align__(16) unsigned short hT[64*HS];
  __shared__ float s_u1[NO], s_u0[NO];
  int t = threadIdx.x, blk = blockIdx.x;
  int lane = t & 63, w = t >> 6;
  int p = lane & 15, q = lane >> 4;
  int pos0 = t >> 4, ch8 = (t & 15)*8, oct = t & 15;

  short8v wfd[4];
#pragma unroll
  for (int ks = 0; ks < 4; ++ks) {
    short8v f;
#pragma unroll
    for (int j = 0; j < 8; ++j) f[j] = (short)f2bf(wd[(w*16+p)*NO + ks*32 + q*8 + j]);
    wfd[ks] = f;
  }
  short8v wfu[2][2];
#pragma unroll
  for (int ntl = 0; ntl < 2; ++ntl)
#pragma unroll
    for (int ks = 0; ks < 2; ++ks) {
      short8v f;
#pragma unroll
      for (int j = 0; j < 8; ++j) f[j] = (short)f2bf(wu[(w*32+ntl*16+p)*NM + ks*32 + q*8 + j]);
      wfu[ntl][ks] = f;
    }
  short8v wfn[4];
  if (do_next) {
#pragma unroll
    for (int ks = 0; ks < 4; ++ks) {
      short8v f;
#pragma unroll
      for (int j = 0; j < 8; ++j) f[j] = (short)f2bf(wdn[(w*16+p)*NO + ks*32 + q*8 + j]);
      wfn[ks] = f;
    }
  }
  float c1 = bnd_stat[(w*16+p)*2];
  float c0 = bd[w*16+p]*c1 + bnd_stat[(w*16+p)*2+1];
  float bdnv = do_next ? bdn[w*16+p] : 0.f;
  for (int i = t; i < NO; i += 256) {
    float scv = bnu_stat[i*2];
    s_u1[i] = scv; s_u0[i] = bu[i]*scv + bnu_stat[i*2+1];
  }

  float ss = 0.f, ss2 = 0.f;

  // prologue: stage tile 0 into xTa
  {
    const unsigned short* s = xb + xb_t(blk*TPW);
    u16x8 v0 = *(const u16x8*)&s[(pos0 +  0)*NO + ch8];
    u16x8 v1 = *(const u16x8*)&s[(pos0 + 16)*NO + ch8];
    u16x8 v2 = *(const u16x8*)&s[(pos0 + 32)*NO + ch8];
    u16x8 v3 = *(const u16x8*)&s[(pos0 + 48)*NO + ch8];
    *(u16x8*)&xTa[(pos0+ 0)*XS + ((oct ^ (((pos0+ 0)>>2)&7))<<3)] = v0;
    *(u16x8*)&xTa[(pos0+16)*XS + ((oct ^ (((pos0+16)>>2)&7))<<3)] = v1;
    *(u16x8*)&xTa[(pos0+32)*XS + ((oct ^ (((pos0+32)>>2)&7))<<3)] = v2;
    *(u16x8*)&xTa[(pos0+48)*XS + ((oct ^ (((pos0+48)>>2)&7))<<3)] = v3;
  }
  __syncthreads();

#pragma unroll
  for (int gi = 0; gi < TPW; ++gi) {
    int T = blk*TPW + gi;
    int bg0 = T*2;
    int b = bg0 >> 11, g0 = bg0 & (NG-1);
    unsigned short* xT  = (gi & 1) ? xTb : xTa;
    unsigned short* xTn = (gi & 1) ? xTa : xTb;
    // --- phase 1: prefetch loads + down-MFMA + prefetch ds_writes
    u16x8 n0, n1, n2, n3;
    if (gi + 1 < TPW) {
      const unsigned short* s = xb + xb_t(T + 1);
      n0 = *(const u16x8*)&s[(pos0 +  0)*NO + ch8];
      n1 = *(const u16x8*)&s[(pos0 + 16)*NO + ch8];
      n2 = *(const u16x8*)&s[(pos0 + 32)*NO + ch8];
      n3 = *(const u16x8*)&s[(pos0 + 48)*NO + ch8];
    }
    {
      f32x4 dacc[4];
#pragma unroll
      for (int mt = 0; mt < 4; ++mt) dacc[mt] = (f32x4){0.f,0.f,0.f,0.f};
#pragma unroll
      for (int ks = 0; ks < 4; ++ks)
#pragma unroll
        for (int mt = 0; mt < 4; ++mt) {
          int pos = mt*16 + p;
          short8v a = *(const short8v*)&xT[pos*XS + (((ks*4+q) ^ ((pos>>2)&7))<<3)];
          dacc[mt] = MFMA(a, wfd[ks], dacc[mt]);
        }
      int ch = w*16 + p;
#pragma unroll
      for (int mt = 0; mt < 4; ++mt)
#pragma unroll
        for (int r = 0; r < 4; ++r) {
          int pos = mt*16 + q*4 + r;
          hT[pos*HS + swzo(ch, pos)] = f2bf(fmaxf(dacc[mt][r]*c1 + c0, 0.f));
        }
    }
    if (gi + 1 < TPW) {
      *(u16x8*)&xTn[(pos0+ 0)*XS + ((oct ^ (((pos0+ 0)>>2)&7))<<3)] = n0;
      *(u16x8*)&xTn[(pos0+16)*XS + ((oct ^ (((pos0+16)>>2)&7))<<3)] = n1;
      *(u16x8*)&xTn[(pos0+32)*XS + ((oct ^ (((pos0+32)>>2)&7))<<3)] = n2;
      *(u16x8*)&xTn[(pos0+48)*XS + ((oct ^ (((pos0+48)>>2)&7))<<3)] = n3;
    }
    __syncthreads();
    // --- phase 2: up-MFMA + residual (per-lane exclusive xT RMW in fragment layout)
    {
      f32x4 uacc[4][2];
#pragma unroll
      for (int mt = 0; mt < 4; ++mt)
#pragma unroll
        for (int ntl = 0; ntl < 2; ++ntl) uacc[mt][ntl] = (f32x4){0.f,0.f,0.f,0.f};
#pragma unroll
      for (int ks = 0; ks < 2; ++ks)
#pragma unroll
        for (int mt = 0; mt < 4; ++mt) {
          int pos = mt*16 + p;
          short8v a = *(const short8v*)&hT[pos*HS + (((ks*4+q) ^ ((pos>>2)&7))<<3)];
#pragma unroll
          for (int ntl = 0; ntl < 2; ++ntl) uacc[mt][ntl] = MFMA(a, wfu[ntl][ks], uacc[mt][ntl]);
        }
#pragma unroll
      for (int ntl = 0; ntl < 2; ++ntl) {
        int ch = w*32 + ntl*16 + p;
        float u1 = s_u1[ch], u0 = s_u0[ch];
#pragma unroll
        for (int mt = 0; mt < 4; ++mt)
#pragma unroll
          for (int r = 0; r < 4; ++r) {
            int pos = mt*16 + q*4 + r;
            int off = pos*XS + swzo(ch, pos);
            float u = uacc[mt][ntl][r]*u1 + u0;
            float xn = fmaxf(u + bf2f(xT[off]), 0.f);
            xT[off] = f2bf(xn);
          }
      }
    }
    __syncthreads();   // xT = new-x complete
    // --- phase 3: writeback (+ next-down stats) from xT
    if (do_next) {
      unsigned short* dst = xb + xb_t(T);
#pragma unroll
      for (int it = 0; it < 4; ++it) {
        int pos = pos0 + it*16;
        u16x8 ov = *(const u16x8*)&xT[pos*XS + ((oct ^ ((pos>>2)&7))<<3)];
        *(u16x8*)&dst[pos*NO + ch8] = ov;
      }
      f32x4 nacc[4];
#pragma unroll
      for (int mt = 0; mt < 4; ++mt) nacc[mt] = (f32x4){0.f,0.f,0.f,0.f};
#pragma unroll
      for (int ks = 0; ks < 4; ++ks)
#pragma unroll
        for (int mt = 0; mt < 4; ++mt) {
          int pos = mt*16 + p;
          short8v a = *(const short8v*)&xT[pos*XS + (((ks*4+q) ^ ((pos>>2)&7))<<3)];
          nacc[mt] = MFMA(a, wfn[ks], nacc[mt]);
        }
#pragma unroll
      for (int mt = 0; mt < 4; ++mt)
#pragma unroll
        for (int r = 0; r < 4; ++r) { float v = nacc[mt][r] + bdnv; ss += v; ss2 += v*v; }
    } else {
      // final f32 output
#pragma unroll
      for (int it = 0; it < 8; ++it) {
        int i = t + it*256;
        int ch = i >> 4, p4 = (i & 15)*4;
        f32x4 o;
#pragma unroll
        for (int r = 0; r < 4; ++r) o[r] = bf2f(xT[(p4+r)*XS + swzo(ch, p4+r)]);
        *(f32x4*)&out[(((size_t)b*NO + ch)*NG + g0)*NK + p4] = o;
      }
    }
    __syncthreads();   // xT free for gi+2's staging
  }
  if (do_next) {
    ss += __shfl_xor(ss, 16); ss += __shfl_xor(ss, 32);
    ss2 += __shfl_xor(ss2, 16); ss2 += __shfl_xor(ss2, 32);
    if (q == 0) {
      part[((size_t)blk*NM + w*16 + p)*2 + 0] = ss;
      part[((size_t)blk*NM + w*16 + p)*2 + 1] = ss2;
    }
  }
}

extern "C" void kernel_launch(void* const* d_in, const int* in_sizes, int n_in,
                              void* d_out, int out_size, void* d_ws, size_t ws_size,
                              hipStream_t stream) {
  const float* lc_xyz   = (const float*)d_in[0];
  const float* lc_feat  = (const float*)d_in[1];
  const float* knn_xyz  = (const float*)d_in[2];
  const float* knn_feat = (const float*)d_in[3];
  const float* w1       = (const float*)d_in[4];
  const float* bn1_g    = (const float*)d_in[5];
  const float* bn1_b    = (const float*)d_in[6];
  const float* wd       = (const float*)d_in[7];
  const float* bd       = (const float*)d_in[8];
  const float* dn_g     = (const float*)d_in[9];
  const float* dn_b     = (const float*)d_in[10];
  const float* wu       = (const float*)d_in[11];
  const float* bu       = (const float*)d_in[12];
  const float* up_g     = (const float*)d_in[13];
  const float* up_b     = (const float*)d_in[14];
  float* out = (float*)d_out;
  float* ws  = (float*)d_ws;
  unsigned short* xb = (unsigned short*)((char*)d_ws + XB_BYTE_OFF);

  k_std_part<<<256, 256, 0, stream>>>(knn_xyz, lc_xyz, ws + OFF_STD_PART);
  k_std_fin<<<1, 256, 0, stream>>>(ws + OFF_STD_PART, ws + OFF_STD);

  k_z1<<<NWGT, 256, 0, stream>>>(knn_feat, lc_feat, w1, xb, ws + OFF_PART);
  k_fin_bn<<<128, 256, 0, stream>>>(ws + OFF_PART, 128, NWGT, bn1_g, bn1_b, ws + OFF_STATA);

  k_x1<<<NWGT, 256, 0, stream>>>(knn_xyz, lc_xyz, wd, bd, xb, ws + OFF_STD,
                                 ws + OFF_STATA, ws + OFF_PART);
  k_fin_bn<<<64, 256, 0, stream>>>(ws + OFF_PART, 64, NWGT, dn_g, dn_b, ws + OFF_STATB);

  k_bstat<<<NWGT, 256, 0, stream>>>(xb, wd, bd, wu, bu, ws + OFF_STATB, ws + OFF_PART);
  k_fin_bn<<<128, 256, 0, stream>>>(ws + OFF_PART, 128, NWGT, up_g, up_b, ws + OFF_STATC);

  k_bfin<<<NWGT, 256, 0, stream>>>(xb, out, wd, bd, wu, bu, ws + OFF_STATB, ws + OFF_STATC,
                                   wd + 64*128, bd + 64, ws + OFF_PART, 1);
  k_fin_bn<<<64, 256, 0, stream>>>(ws + OFF_PART, 64, NWGT, dn_g + 64, dn_b + 64, ws + OFF_STATB);

  k_bstat<<<NWGT, 256, 0, stream>>>(xb, wd + 64*128, bd + 64, wu + 128*64, bu + 128,
                                    ws + OFF_STATB, ws + OFF_PART);
  k_fin_bn<<<128, 256, 0, stream>>>(ws + OFF_PART, 128, NWGT, up_g + 128, up_b + 128, ws + OFF_STATC);

  k_bfin<<<NWGT, 256, 0, stream>>>(xb, out, wd + 64*128, bd + 64, wu + 128*64, bu + 128,
                                   ws + OFF_STATB, ws + OFF_STATC,
                                   (const float*)nullptr, (const float*)nullptr,
                                   ws + OFF_PART, 0);
}